// Round 12
// baseline (480.649 us; speedup 1.0000x reference)
//
#include <hip/hip_runtime.h>
#include <hip/hip_cooperative_groups.h>
#include <math.h>

namespace cg = cooperative_groups;

#define HH 256
#define WW 256
#define NN (HH * WW)

typedef _Float16 f16;
typedef _Float16 f16x4 __attribute__((ext_vector_type(4)));
typedef _Float16 f16x8 __attribute__((ext_vector_type(8)));
typedef float f32x4 __attribute__((ext_vector_type(4)));

#define OQ 75264  // qkv B-frag base inside BF (f16 units)

__device__ inline float dot8p(f16x8 a, f16x8 b, float acc) {
#if __has_builtin(__builtin_amdgcn_fdot2)
  acc = __builtin_amdgcn_fdot2(__builtin_shufflevector(a, a, 0, 1),
                               __builtin_shufflevector(b, b, 0, 1), acc, false);
  acc = __builtin_amdgcn_fdot2(__builtin_shufflevector(a, a, 2, 3),
                               __builtin_shufflevector(b, b, 2, 3), acc, false);
  acc = __builtin_amdgcn_fdot2(__builtin_shufflevector(a, a, 4, 5),
                               __builtin_shufflevector(b, b, 4, 5), acc, false);
  acc = __builtin_amdgcn_fdot2(__builtin_shufflevector(a, a, 6, 7),
                               __builtin_shufflevector(b, b, 6, 7), acc, false);
  return acc;
#else
#pragma unroll
  for (int i = 0; i < 8; ++i) acc += (float)a[i] * (float)b[i];
  return acc;
#endif
}

// ---------------------------------------------------------------------------
// Weight repack element e -> BF[e] (shared by mega phase 0 and prep_kernel).
// BF: L0 @0 [nt][lane][j]; L1 @1536 / L2 @29184 / L3 @56832
// [tap][kc][nt][lane][j]; qkv QF @OQ, KF @OQ+1024, VF @OQ+2048.
// ---------------------------------------------------------------------------
__device__ __forceinline__ float repack_elem(
    int e, const float* __restrict__ w0, const float* __restrict__ w1,
    const float* __restrict__ w2, const float* __restrict__ w3,
    const float* __restrict__ qw, const float* __restrict__ kw,
    const float* __restrict__ vw) {
  const int O1 = 1536, O2 = O1 + 27648, O3 = O2 + 27648;
  float val = 0.f;
  if (e >= OQ) {
    int idx = e - OQ;
    int mat = idx >> 10;
    int r = idx & 1023;
    int nt = r >> 9;
    int ln = (r >> 3) & 63;
    int j = r & 7;
    int nn = ln & 15, qd = ln >> 4;
    int ci = qd * 8 + j, co = nt * 16 + nn;
    const float* w = (mat == 0) ? qw : (mat == 1) ? kw : vw;
    if (ci < 24 && co < 24) val = w[co * 24 + ci];
  } else if (e < O1) {
    int j = e & 7;
    int ln = (e >> 3) & 63;
    int nt = e >> 9;
    int nn = ln & 15, qd = ln >> 4;
    int k = qd * 8 + j;
    int cout = nt * 16 + nn;
    if (k < 27) {
      int tap = k / 3, ci = k - tap * 3;
      val = w0[(cout * 3 + ci) * 9 + tap];
    }
  } else {
    const float* w;
    int COUT, idx;
    if (e < O2)      { w = w1; COUT = 48; idx = e - O1; }
    else if (e < O3) { w = w2; COUT = 48; idx = e - O2; }
    else             { w = w3; COUT = 24; idx = e - O3; }
    const int NT = (COUT == 48) ? 3 : 2;
    int j = idx & 7;
    int ln = (idx >> 3) & 63;
    int rest = idx >> 9;
    int nt = rest % NT;
    int q2 = rest / NT;
    int kc = q2 & 1;
    int tap = q2 >> 1;
    int nn = ln & 15, qd = ln >> 4;
    int ci = kc * 32 + qd * 8 + j;
    int cout = nt * 16 + nn;
    if (ci < 48 && cout < COUT) val = w[(cout * 48 + ci) * 9 + tap];
  }
  return val;
}

// ---------------------------------------------------------------------------
// 3x3 conv layer body. 16x8 px tile; halo 18x10 = 180 slots x 144B LDS;
// tap-major B-frags. FUSE: + 1x1 skip of x, writes ABh (NHWC f16 32ch/px).
// Trailing __syncthreads so back-to-back calls can't race LDS restaging.
// ---------------------------------------------------------------------------
template <int NT, int COUT, bool FUSE>
__device__ __forceinline__ void conv_layer(
    const f16* __restrict__ in, const f16* __restrict__ bfr,
    const float* __restrict__ bias, f16* __restrict__ outh,
    const float* __restrict__ xsrc, const float* __restrict__ skw,
    const float* __restrict__ skb, char* smem, int tid, int bx, int by,
    int z) {
  float* xt = (float*)(smem + 180 * 144);
  const int lane = tid & 63, wave = tid >> 6;
  const int n = lane & 15, quad = lane >> 4;
  const f16* inz = in + (size_t)z * NN * 48;

  if (tid < 180) {
    int p = tid;
    int yy = p / 18, xx = p - yy * 18;
    int gy = by + yy - 1, gx = bx + xx - 1;
    float4* dst = (float4*)(smem + p * 144);
    if (gy >= 0 && gy < HH && gx >= 0 && gx < WW) {
      const float4* s = (const float4*)(inz + ((size_t)gy * WW + gx) * 48);
      float4 a0 = s[0], a1 = s[1], a2 = s[2], a3 = s[3], a4 = s[4], a5 = s[5];
      dst[0] = a0; dst[1] = a1; dst[2] = a2;
      dst[3] = a3; dst[4] = a4; dst[5] = a5;
      dst[6] = make_float4(0, 0, 0, 0);
      dst[7] = make_float4(0, 0, 0, 0);
    } else {
      float4 zz = make_float4(0, 0, 0, 0);
#pragma unroll
      for (int c = 0; c < 8; ++c) dst[c] = zz;
    }
  }
  if (FUSE) {
    for (int i = tid; i < 384; i += 256) {
      int c = i >> 7, p = i & 127;
      xt[i] = xsrc[(size_t)z * 3 * NN + c * NN + (by + (p >> 4)) * WW + bx +
                   (p & 15)];
    }
  }
  __syncthreads();

  f32x4 acc[2][NT];
#pragma unroll
  for (int nt = 0; nt < NT; ++nt) {
    int cc = nt * 16 + n;
    float bv = (cc < COUT) ? bias[cc] : 0.f;
#pragma unroll
    for (int i = 0; i < 2; ++i) acc[i][nt] = (f32x4){bv, bv, bv, bv};
  }

  const int r0 = wave * 2;
#pragma unroll 1
  for (int tap = 0; tap < 9; ++tap) {
    const int dy = tap / 3, dx = tap - dy * 3;
    f16x8 B[2][NT];
#pragma unroll
    for (int kc = 0; kc < 2; ++kc)
#pragma unroll
      for (int nt = 0; nt < NT; ++nt)
        B[kc][nt] = *(const f16x8*)(bfr +
                                    (((tap * 2 + kc) * NT + nt) * 64 + lane) * 8);
#pragma unroll
    for (int i = 0; i < 2; ++i) {
      const int p = (r0 + i + dy) * 18 + (n + dx);
      const char* ap = smem + p * 144;
      f16x8 a0 = *(const f16x8*)(ap + quad * 16);
      f16x8 a1 = *(const f16x8*)(ap + 64 + quad * 16);
#pragma unroll
      for (int nt = 0; nt < NT; ++nt)
        acc[i][nt] = __builtin_amdgcn_mfma_f32_16x16x32_f16(a0, B[0][nt],
                                                            acc[i][nt], 0, 0, 0);
#pragma unroll
      for (int nt = 0; nt < NT; ++nt)
        acc[i][nt] = __builtin_amdgcn_mfma_f32_16x16x32_f16(a1, B[1][nt],
                                                            acc[i][nt], 0, 0, 0);
    }
  }

  if (!FUSE) {
    f16* oz = outh + (size_t)z * NN * 48;
#pragma unroll
    for (int i = 0; i < 2; ++i) {
      int y = by + r0 + i;
#pragma unroll
      for (int nt = 0; nt < NT; ++nt)
#pragma unroll
        for (int reg = 0; reg < 4; ++reg)
          oz[((size_t)y * WW + bx + quad * 4 + reg) * 48 + nt * 16 + n] =
              (f16)fmaxf(acc[i][nt][reg], 0.f);
    }
  } else {
    f16* oz = outh + (size_t)z * NN * 32;
#pragma unroll
    for (int i = 0; i < 2; ++i) {
      int y = by + r0 + i;
#pragma unroll
      for (int nt = 0; nt < NT; ++nt) {
        int cc = nt * 16 + n;
        float s0 = 0.f, s1 = 0.f, s2 = 0.f, sbv = 0.f;
        if (cc < 24) {
          s0 = skw[cc * 3 + 0];
          s1 = skw[cc * 3 + 1];
          s2 = skw[cc * 3 + 2];
          sbv = skb[cc];
        }
#pragma unroll
        for (int reg = 0; reg < 4; ++reg) {
          float v = 0.f;
          if (cc < 24) {
            int pl = (r0 + i) * 16 + quad * 4 + reg;
            float sk = sbv + s0 * xt[pl] + s1 * xt[128 + pl] + s2 * xt[256 + pl];
            v = fmaxf(acc[i][nt][reg], 0.f) + sk;
          }
          oz[((size_t)(y * WW + bx + quad * 4 + reg)) * 32 + cc] = (f16)v;
        }
      }
    }
  }
  __syncthreads();  // safe LDS reuse on the next call
}

// ---------------------------------------------------------------------------
// MEGAKERNEL: 512 blocks x 256 thr, cooperative (2 blocks/CU needed vs 4/CU
// capacity -> 2x co-residency margin; R11 launched 1024 = exact capacity and
// the launch was rejected). Conv phases grid-stride 2 tile-jobs per block.
// ---------------------------------------------------------------------------
__global__ __launch_bounds__(256, 4) void mega(
    const float* __restrict__ x, const float* __restrict__ w0,
    const float* __restrict__ b0, const float* __restrict__ w1,
    const float* __restrict__ b1, const float* __restrict__ w2,
    const float* __restrict__ b2, const float* __restrict__ w3,
    const float* __restrict__ b3, const float* __restrict__ sw,
    const float* __restrict__ sb, const float* __restrict__ qw,
    const float* __restrict__ qb, const float* __restrict__ kw,
    const float* __restrict__ kb, const float* __restrict__ vw,
    const float* __restrict__ vb, float* __restrict__ out,
    f16* __restrict__ ACT0, f16* __restrict__ ACT1, f16* __restrict__ ABh,
    f16* __restrict__ BF) {
  extern __shared__ char smem[];
  cg::grid_group grid = cg::this_grid();
  const int tid = threadIdx.x;
  const int bz = blockIdx.x;
  const int lane = tid & 63, wave = tid >> 6;
  const int n = lane & 15, quad = lane >> 4;

  // ---------------- Phase 0: weight repack (306*256 = 78336 elems)
  if (bz < 306) {
    int e = bz * 256 + tid;
    BF[e] = (f16)repack_elem(e, w0, w1, w2, w3, qw, kw, vw);
  }
  grid.sync();

  // ---------------- Phase 1: conv0 (3->48) direct im2col, 2 jobs/block
#pragma unroll 1
  for (int job = bz; job < 1024; job += 512) {
    const int z = job >> 9, tt = job & 511;
    const int bx = (tt & 15) * 16, by = (tt >> 4) * 8;
    if (tid < 128) {
      int yy = tid >> 4, xc = tid & 15;
      int gy = by + yy, gx = bx + xc;
      const float* xz = x + (size_t)z * 3 * NN;
      f16* row = (f16*)(smem + tid * 80);
#pragma unroll
      for (int tap = 0; tap < 9; ++tap) {
        int dy = tap / 3, dx = tap - (tap / 3) * 3;
        int sy = gy + dy - 1, sx = gx + dx - 1;
        f16 c0 = (f16)0.f, c1 = c0, c2 = c0;
        if (sy >= 0 && sy < HH && sx >= 0 && sx < WW) {
          int o = sy * WW + sx;
          c0 = (f16)xz[o];
          c1 = (f16)xz[NN + o];
          c2 = (f16)xz[2 * NN + o];
        }
        row[tap * 3 + 0] = c0;
        row[tap * 3 + 1] = c1;
        row[tap * 3 + 2] = c2;
      }
#pragma unroll
      for (int k = 27; k < 32; ++k) row[k] = (f16)0.f;
    }
    __syncthreads();

    f16x8 B0[3];
#pragma unroll
    for (int nt = 0; nt < 3; ++nt)
      B0[nt] = *(const f16x8*)(BF + (nt * 64 + lane) * 8);
    f16* oz = ACT0 + (size_t)z * NN * 48;
#pragma unroll
    for (int u = 0; u < 2; ++u) {
      int T = wave * 2 + u;  // tile row 0..7
      f16x8 a = *(const f16x8*)(smem + (T * 16 + n) * 80 + quad * 16);
#pragma unroll
      for (int nt = 0; nt < 3; ++nt) {
        float bv = b0[nt * 16 + n];
        f32x4 acc = {bv, bv, bv, bv};
        acc = __builtin_amdgcn_mfma_f32_16x16x32_f16(a, B0[nt], acc, 0, 0, 0);
        int gy = by + T;
#pragma unroll
        for (int reg = 0; reg < 4; ++reg)
          oz[((size_t)gy * WW + bx + quad * 4 + reg) * 48 + nt * 16 + n] =
              (f16)fmaxf(acc[reg], 0.f);
      }
    }
    __syncthreads();
  }
  grid.sync();

  // ---------------- Phases 2-4: conv1, conv2, conv3+skip (2 jobs each)
#pragma unroll 1
  for (int job = bz; job < 1024; job += 512) {
    const int z = job >> 9, tt = job & 511;
    conv_layer<3, 48, false>(ACT0, BF + 1536, b1, ACT1, nullptr, nullptr,
                             nullptr, smem, tid, (tt & 15) * 16, (tt >> 4) * 8,
                             z);
  }
  grid.sync();
#pragma unroll 1
  for (int job = bz; job < 1024; job += 512) {
    const int z = job >> 9, tt = job & 511;
    conv_layer<3, 48, false>(ACT1, BF + 29184, b2, ACT0, nullptr, nullptr,
                             nullptr, smem, tid, (tt & 15) * 16, (tt >> 4) * 8,
                             z);
  }
  grid.sync();
#pragma unroll 1
  for (int job = bz; job < 1024; job += 512) {
    const int z = job >> 9, tt = job & 511;
    conv_layer<2, 24, true>(ACT0, BF + 56832, b3, ABh, x, sw, sb, smem, tid,
                            (tt & 15) * 16, (tt >> 4) * 8, z);
  }
  grid.sync();

  // ---------------- Phase 5: attention (+ fused Q), one 16x8 tile per block
  {
    f16* kv = (f16*)smem;                        // 320 slots * 56 f16
    f16* Wq = (f16*)(smem + 35840);              // 576 f16
    float* Qbv = (float*)(smem + 35840 + 1152);  // 24 f32
    const int bxA = (bz & 15) * 16, byA = (bz >> 4) * 8;

    for (int i = tid; i < 576; i += 256) Wq[i] = (f16)qw[i];
    if (tid < 24) Qbv[tid] = qb[tid];

    for (int idx = tid; idx < 1232; idx += 256) {
      int slot = idx >> 2, c = idx & 3;
      int row = slot / 22, pxl = slot - row * 22;
      int gy = byA + row - 3, gx = bxA + pxl - 3;
      f16x8 v = {};
      if (gy >= 0 && gy < HH && gx >= 0 && gx < WW)
        v = *(const f16x8*)(ABh + ((size_t)(gy * WW + gx)) * 32 + c * 8);
      *(f16x8*)(kv + slot * 56 + c * 8) = v;
    }
    __syncthreads();

    const int t7 = tid & 127, half = tid >> 7;  // wave-uniform half
    const int yl = t7 >> 4, xl = t7 & 15;
    const int pg = (byA + yl) * WW + bxA + xl;

    const f16* cs = kv + ((yl + 3) * 22 + (xl + 3)) * 56;
    f16x8 a0 = *(const f16x8*)(cs);
    f16x8 a1 = *(const f16x8*)(cs + 8);
    f16x8 a2 = *(const f16x8*)(cs + 16);

    const f16* bhp = ABh + (size_t)NN * 32 + (size_t)pg * 32;
    f16x8 bb0 = *(const f16x8*)(bhp);
    f16x8 bb1 = *(const f16x8*)(bhp + 8);
    f16x8 bb2 = *(const f16x8*)(bhp + 16);
    float qf[24];
#pragma unroll
    for (int co = 0; co < 24; ++co) {
      float acc = Qbv[co];
      acc = dot8p(bb0, *(const f16x8*)(Wq + co * 24), acc);
      acc = dot8p(bb1, *(const f16x8*)(Wq + co * 24 + 8), acc);
      acc = dot8p(bb2, *(const f16x8*)(Wq + co * 24 + 16), acc);
      qf[co] = acc;
    }
    f16x8 q0, q1, q2;
#pragma unroll
    for (int c = 0; c < 8; ++c) {
      q0[c] = (f16)qf[c];
      q1[c] = (f16)qf[8 + c];
      q2[c] = (f16)qf[16 + c];
    }
    __syncthreads();  // snapshots + q done before in-place overwrite

    {
      f16x8 KF[2], VF[2];
#pragma unroll
      for (int nt = 0; nt < 2; ++nt) {
        KF[nt] = *(const f16x8*)(BF + OQ + 1024 + (nt * 64 + lane) * 8);
        VF[nt] = *(const f16x8*)(BF + OQ + 2048 + (nt * 64 + lane) * 8);
      }
      float kbias[2], vbias[2];
#pragma unroll
      for (int nt = 0; nt < 2; ++nt) {
        int cc = nt * 16 + n;
        kbias[nt] = (cc < 24) ? kb[cc] : 0.f;
        vbias[nt] = (cc < 24) ? vb[cc] : 0.f;
      }
      for (int t = wave; t < 20; t += 4) {
        f16x8 a8 = *(const f16x8*)(kv + (t * 16 + n) * 56 + quad * 8);
#pragma unroll
        for (int nt = 0; nt < 2; ++nt) {
          f32x4 ak = {kbias[nt], kbias[nt], kbias[nt], kbias[nt]};
          f32x4 av = {vbias[nt], vbias[nt], vbias[nt], vbias[nt]};
          ak = __builtin_amdgcn_mfma_f32_16x16x32_f16(a8, KF[nt], ak, 0, 0, 0);
          av = __builtin_amdgcn_mfma_f32_16x16x32_f16(a8, VF[nt], av, 0, 0, 0);
          int cc = nt * 16 + n;
          if (cc < 24) {
#pragma unroll
            for (int reg = 0; reg < 4; ++reg) {
              f16* slot = kv + (t * 16 + quad * 4 + reg) * 56;
              slot[cc] = (f16)ak[reg];
              slot[24 + cc] = (f16)av[reg];
            }
          }
        }
      }
    }
    __syncthreads();

    float s[25];
    float m = -3e38f;
#pragma unroll
    for (int i = 0; i < 25; ++i) {
      int pp = half * 25 + i;
      if (pp < 49) {
        int dy = pp / 7, dx = pp - (pp / 7) * 7;
        const f16* base = kv + ((yl + dy) * 22 + (xl + dx)) * 56;
        f16x8 k0 = *(const f16x8*)(base);
        f16x8 k1 = *(const f16x8*)(base + 8);
        f16x8 k2 = *(const f16x8*)(base + 16);
        float d = 0.f;
        d = dot8p(q0, k0, d);
        d = dot8p(q1, k1, d);
        d = dot8p(q2, k2, d);
        s[i] = d * 0.20412414523193154f;  // 1/sqrt(24)
        m = fmaxf(m, s[i]);
      } else {
        s[i] = -3e38f;
      }
    }
    float den = 0.f;
#pragma unroll
    for (int i = 0; i < 25; ++i) {
      float e = __expf(s[i] - m);
      s[i] = e;
      den += e;
    }

    f16x8 y0 = {}, y1 = {}, y2 = {};
#pragma unroll
    for (int i = 0; i < 25; ++i) {
      int pp = half * 25 + i;
      if (pp < 49) {
        int dy = pp / 7, dx = pp - (pp / 7) * 7;
        const f16* base = kv + ((yl + dy) * 22 + (xl + dx)) * 56 + 24;
        f16 wh = (f16)s[i];
        f16x8 w8 = {wh, wh, wh, wh, wh, wh, wh, wh};
        f16x8 v0 = *(const f16x8*)(base);
        f16x8 v1 = *(const f16x8*)(base + 8);
        f16x8 v2 = *(const f16x8*)(base + 16);
        y0 = v0 * w8 + y0;
        y1 = v1 * w8 + y1;
        y2 = v2 * w8 + y2;
      }
    }
    __syncthreads();  // kv reads done -> reuse as exchange

    if (half == 1) {
      f16* ex = kv + t7 * 56;
      *(f16x8*)(ex) = y0;
      *(f16x8*)(ex + 8) = y1;
      *(f16x8*)(ex + 16) = y2;
      float* mf = (float*)(ex + 24);
      mf[0] = m;
      mf[1] = den;
    }
    __syncthreads();

    if (half == 0) {
      const f16* ex = kv + t7 * 56;
      f16x8 yb0 = *(const f16x8*)(ex);
      f16x8 yb1 = *(const f16x8*)(ex + 8);
      f16x8 yb2 = *(const f16x8*)(ex + 16);
      const float* mf = (const float*)(ex + 24);
      float mB = mf[0], dB = mf[1];
      float M = fmaxf(m, mB);
      float fa = __expf(m - M), fb = __expf(mB - M);
      float inv = 1.f / (den * fa + dB * fb);
#pragma unroll
      for (int c = 0; c < 8; ++c) {
        out[(size_t)c * NN + pg] =
            ((float)y0[c] * fa + (float)yb0[c] * fb) * inv + (float)a0[c];
        out[(size_t)(8 + c) * NN + pg] =
            ((float)y1[c] * fa + (float)yb1[c] * fb) * inv + (float)a1[c];
        out[(size_t)(16 + c) * NN + pg] =
            ((float)y2[c] * fa + (float)yb2[c] * fb) * inv + (float)a2[c];
      }
    } else {
#pragma unroll
      for (int c = 0; c < 8; ++c) {
        out[(size_t)(24 + c) * NN + pg] = (float)bb0[c];
        out[(size_t)(32 + c) * NN + pg] = (float)bb1[c];
        out[(size_t)(40 + c) * NN + pg] = (float)bb2[c];
      }
    }
  }
}

// ===========================================================================
// FALLBACK PATH (R10, proven 158 µs) — used if cooperative launch fails.
// ===========================================================================
__global__ __launch_bounds__(256) void prep_kernel(
    const float* __restrict__ x, const float* __restrict__ w0,
    const float* __restrict__ w1, const float* __restrict__ w2,
    const float* __restrict__ w3, const float* __restrict__ qw,
    const float* __restrict__ kw, const float* __restrict__ vw,
    f16* __restrict__ xh, f16* __restrict__ bf) {
  if (blockIdx.x < 512) {
    int p = blockIdx.x * 256 + threadIdx.x;
    int z = p >= NN;
    int q = p - z * NN;
    const float* xz = x + (size_t)z * 3 * NN;
    f16x4 v;
    v[0] = (f16)xz[q];
    v[1] = (f16)xz[NN + q];
    v[2] = (f16)xz[2 * NN + q];
    v[3] = (f16)0.f;
    *(f16x4*)(xh + (size_t)p * 4) = v;
    return;
  }
  int e = (blockIdx.x - 512) * 256 + threadIdx.x;
  if (e >= OQ + 3072) return;
  bf[e] = (f16)repack_elem(e, w0, w1, w2, w3, qw, kw, vw);
}

__global__ __launch_bounds__(256, 2) void conv0_gemm(
    const f16* __restrict__ xh, const f16* __restrict__ bf0,
    const float* __restrict__ bias, f16* __restrict__ outh) {
  extern __shared__ char smem[];
  const int tid = threadIdx.x;
  const int lane = tid & 63, wave = tid >> 6;
  const int n = lane & 15, quad = lane >> 4;
  const int bx = blockIdx.x * 16, by = blockIdx.y * 16, z = blockIdx.z;
  const f16* xz = xh + (size_t)z * NN * 4;

  {
    int p = tid, y = p >> 4, xcol = p & 15;
    int gy = by + y, gx = bx + xcol;
    f16* row = (f16*)(smem + p * 80);
#pragma unroll
    for (int tap = 0; tap < 9; ++tap) {
      int dy = tap / 3, dx = tap - (tap / 3) * 3;
      int sy = gy + dy - 1, sx = gx + dx - 1;
      f16 c0 = (f16)0.f, c1 = c0, c2 = c0;
      if (sy >= 0 && sy < HH && sx >= 0 && sx < WW) {
        const f16* s = xz + ((size_t)sy * WW + sx) * 4;
        c0 = s[0]; c1 = s[1]; c2 = s[2];
      }
      row[tap * 3 + 0] = c0;
      row[tap * 3 + 1] = c1;
      row[tap * 3 + 2] = c2;
    }
#pragma unroll
    for (int k = 27; k < 32; ++k) row[k] = (f16)0.f;
  }
  __syncthreads();

  f32x4 acc[4][3];
#pragma unroll
  for (int nt = 0; nt < 3; ++nt) {
    float bv = bias[nt * 16 + n];
#pragma unroll
    for (int i = 0; i < 4; ++i) acc[i][nt] = (f32x4){bv, bv, bv, bv};
  }
  f16x8 B[3];
#pragma unroll
  for (int nt = 0; nt < 3; ++nt)
    B[nt] = *(const f16x8*)(bf0 + (nt * 64 + lane) * 8);
#pragma unroll
  for (int i = 0; i < 4; ++i) {
    int r = wave * 4 + i;
    f16x8 a = *(const f16x8*)(smem + (r * 16 + n) * 80 + quad * 16);
#pragma unroll
    for (int nt = 0; nt < 3; ++nt)
      acc[i][nt] =
          __builtin_amdgcn_mfma_f32_16x16x32_f16(a, B[nt], acc[i][nt], 0, 0, 0);
  }

  f16* oz = outh + (size_t)z * NN * 48;
#pragma unroll
  for (int i = 0; i < 4; ++i) {
    int y = by + wave * 4 + i;
#pragma unroll
    for (int nt = 0; nt < 3; ++nt)
#pragma unroll
      for (int reg = 0; reg < 4; ++reg)
        oz[((size_t)y * WW + bx + quad * 4 + reg) * 48 + nt * 16 + n] =
            (f16)fmaxf(acc[i][nt][reg], 0.f);
  }
}

template <int NT, int COUT, bool FUSE>
__global__ __launch_bounds__(256, 4) void gemm_conv(
    const f16* __restrict__ in, const f16* __restrict__ bfr,
    const float* __restrict__ bias, f16* __restrict__ outh,
    const float* __restrict__ xsrc, const float* __restrict__ skw,
    const float* __restrict__ skb) {
  extern __shared__ char smem[];
  conv_layer<NT, COUT, FUSE>(in, bfr, bias, outh, xsrc, skw, skb, smem,
                             threadIdx.x, blockIdx.x * 16, blockIdx.y * 8,
                             blockIdx.z);
}

__global__ __launch_bounds__(256) void q_mfma(const f16* __restrict__ ABh,
                                              const f16* __restrict__ bf,
                                              const float* __restrict__ qb,
                                              f16* __restrict__ Qh) {
  const int tid = threadIdx.x;
  const int lane = tid & 63, wave = tid >> 6;
  const int n = lane & 15, quad = lane >> 4;
  const f16* src = ABh + (size_t)NN * 32;
  f16x8 QF[2];
#pragma unroll
  for (int nt = 0; nt < 2; ++nt)
    QF[nt] = *(const f16x8*)(bf + OQ + (nt * 64 + lane) * 8);
  float qbias[2];
#pragma unroll
  for (int nt = 0; nt < 2; ++nt) {
    int cc = nt * 16 + n;
    qbias[nt] = (cc < 24) ? qb[cc] : 0.f;
  }
#pragma unroll
  for (int t = 0; t < 4; ++t) {
    int T = blockIdx.x * 16 + wave * 4 + t;
    size_t p0 = (size_t)T * 16;
    f16x8 a8 = *(const f16x8*)(src + p0 * 32 + n * 32 + quad * 8);
#pragma unroll
    for (int nt = 0; nt < 2; ++nt) {
      f32x4 acc = {qbias[nt], qbias[nt], qbias[nt], qbias[nt]};
      acc = __builtin_amdgcn_mfma_f32_16x16x32_f16(a8, QF[nt], acc, 0, 0, 0);
      int cc = nt * 16 + n;
      if (cc < 24) {
#pragma unroll
        for (int reg = 0; reg < 4; ++reg)
          Qh[(p0 + quad * 4 + reg) * 24 + cc] = (f16)acc[reg];
      }
    }
  }
}

__global__ __launch_bounds__(256, 3) void attn_kernel(
    const f16* __restrict__ Qh, const f16* __restrict__ ABh,
    const f16* __restrict__ bf, const float* __restrict__ kb,
    const float* __restrict__ vb, float* __restrict__ out) {
  extern __shared__ f16 kv[];  // 544 slots * 56 f16
  const int tid = threadIdx.x;
  const int lane = tid & 63, wave = tid >> 6;
  const int n16 = lane & 15, quad = lane >> 4;
  const int bx = blockIdx.x * 32, by = blockIdx.y * 8;
  const int xl = tid & 31, yl = tid >> 5;
  const int p = (by + yl) * WW + bx + xl;
  const f16* ah = ABh;
  const f16* bh = ABh + (size_t)NN * 32;

  f16x8 q0 = *(const f16x8*)(Qh + (size_t)p * 24);
  f16x8 q1 = *(const f16x8*)(Qh + (size_t)p * 24 + 8);
  f16x8 q2 = *(const f16x8*)(Qh + (size_t)p * 24 + 16);

  for (int idx = tid; idx < 2128; idx += 256) {
    int row = idx / 152;
    int rem = idx - row * 152;
    int pxl = rem >> 2;
    int c = rem & 3;
    int gy = by + row - 3, gx = bx + pxl - 3;
    f16x8 v = {};
    if (gy >= 0 && gy < HH && gx >= 0 && gx < WW)
      v = *(const f16x8*)(ah + ((size_t)(gy * WW + gx)) * 32 + c * 8);
    *(f16x8*)(kv + (row * 38 + pxl) * 56 + c * 8) = v;
  }
  __syncthreads();

  const f16* cs = kv + ((yl + 3) * 38 + xl + 3) * 56;
  f16x8 a0 = *(const f16x8*)(cs);
  f16x8 a1 = *(const f16x8*)(cs + 8);
  f16x8 a2 = *(const f16x8*)(cs + 16);
  __syncthreads();

  {
    f16x8 KF[2], VF[2];
#pragma unroll
    for (int nt = 0; nt < 2; ++nt) {
      KF[nt] = *(const f16x8*)(bf + OQ + 1024 + (nt * 64 + lane) * 8);
      VF[nt] = *(const f16x8*)(bf + OQ + 2048 + (nt * 64 + lane) * 8);
    }
    float kbias[2], vbias[2];
#pragma unroll
    for (int nt = 0; nt < 2; ++nt) {
      int cc = nt * 16 + n16;
      kbias[nt] = (cc < 24) ? kb[cc] : 0.f;
      vbias[nt] = (cc < 24) ? vb[cc] : 0.f;
    }
    for (int t = wave; t < 34; t += 4) {
      f16x8 a8 = *(const f16x8*)(kv + (t * 16 + n16) * 56 + quad * 8);
#pragma unroll
      for (int nt = 0; nt < 2; ++nt) {
        f32x4 ak = {kbias[nt], kbias[nt], kbias[nt], kbias[nt]};
        f32x4 av = {vbias[nt], vbias[nt], vbias[nt], vbias[nt]};
        ak = __builtin_amdgcn_mfma_f32_16x16x32_f16(a8, KF[nt], ak, 0, 0, 0);
        av = __builtin_amdgcn_mfma_f32_16x16x32_f16(a8, VF[nt], av, 0, 0, 0);
        int cc = nt * 16 + n16;
        if (cc < 24) {
#pragma unroll
          for (int reg = 0; reg < 4; ++reg) {
            f16* slot = kv + (t * 16 + quad * 4 + reg) * 56;
            slot[cc] = (f16)ak[reg];
            slot[24 + cc] = (f16)av[reg];
          }
        }
      }
    }
  }
  __syncthreads();

  float s[49];
#pragma unroll
  for (int pp = 0; pp < 49; ++pp) {
    int dy = pp / 7, dx = pp - dy * 7;
    const f16* base = kv + ((yl + dy) * 38 + xl + dx) * 56;
    f16x8 k0 = *(const f16x8*)(base);
    f16x8 k1 = *(const f16x8*)(base + 8);
    f16x8 k2 = *(const f16x8*)(base + 16);
    float d = 0.f;
    d = dot8p(q0, k0, d);
    d = dot8p(q1, k1, d);
    d = dot8p(q2, k2, d);
    s[pp] = d * 0.20412414523193154f;
  }

  float m = s[0];
#pragma unroll
  for (int pp = 1; pp < 49; ++pp) m = fmaxf(m, s[pp]);
  float den = 0.f;
#pragma unroll
  for (int pp = 0; pp < 49; ++pp) {
    float e = __expf(s[pp] - m);
    s[pp] = e;
    den += e;
  }
  const float inv = 1.f / den;

  f16x8 y0 = {}, y1 = {}, y2 = {};
#pragma unroll
  for (int pp = 0; pp < 49; ++pp) {
    int dy = pp / 7, dx = pp - dy * 7;
    const f16* base = kv + ((yl + dy) * 38 + xl + dx) * 56 + 24;
    f16 wh = (f16)(s[pp] * inv);
    f16x8 w8 = {wh, wh, wh, wh, wh, wh, wh, wh};
    f16x8 v0 = *(const f16x8*)(base);
    f16x8 v1 = *(const f16x8*)(base + 8);
    f16x8 v2 = *(const f16x8*)(base + 16);
    y0 = v0 * w8 + y0;
    y1 = v1 * w8 + y1;
    y2 = v2 * w8 + y2;
  }

  f16x8 b0 = *(const f16x8*)(bh + (size_t)p * 32);
  f16x8 b1 = *(const f16x8*)(bh + (size_t)p * 32 + 8);
  f16x8 b2 = *(const f16x8*)(bh + (size_t)p * 32 + 16);
#pragma unroll
  for (int c = 0; c < 8; ++c) {
    out[(size_t)c * NN + p] = (float)y0[c] + (float)a0[c];
    out[(size_t)(8 + c) * NN + p] = (float)y1[c] + (float)a1[c];
    out[(size_t)(16 + c) * NN + p] = (float)y2[c] + (float)a2[c];
    out[(size_t)(24 + c) * NN + p] = (float)b0[c];
    out[(size_t)(32 + c) * NN + p] = (float)b1[c];
    out[(size_t)(40 + c) * NN + p] = (float)b2[c];
  }
}

// ---------------------------------------------------------------------------
extern "C" void kernel_launch(void* const* d_in, const int* in_sizes, int n_in,
                              void* d_out, int out_size, void* d_ws,
                              size_t ws_size, hipStream_t stream) {
  const float* x = (const float*)d_in[0];
  const float* w0 = (const float*)d_in[1];
  const float* b0 = (const float*)d_in[2];
  const float* w1 = (const float*)d_in[3];
  const float* b1 = (const float*)d_in[4];
  const float* w2 = (const float*)d_in[5];
  const float* b2 = (const float*)d_in[6];
  const float* w3 = (const float*)d_in[7];
  const float* b3 = (const float*)d_in[8];
  const float* sw = (const float*)d_in[9];
  const float* sb = (const float*)d_in[10];
  const float* qw = (const float*)d_in[11];
  const float* qb = (const float*)d_in[12];
  const float* kw = (const float*)d_in[13];
  const float* kb = (const float*)d_in[14];
  const float* vw = (const float*)d_in[15];
  const float* vb = (const float*)d_in[16];
  float* out = (float*)d_out;

  // workspace (f16 units), disjoint; shared by both paths:
  f16* base = (f16*)d_ws;
  f16* ACT0 = base;                      // 96*NN
  f16* ACT1 = base + (size_t)96 * NN;    // 96*NN
  f16* ABh = base + (size_t)192 * NN;    // 64*NN
  f16* Qh = base + (size_t)256 * NN;     // 24*NN (fallback only)
  f16* BF = base + (size_t)280 * NN;     // 78336
  f16* XH = base + (size_t)282 * NN;     // 8*NN (fallback only)

  int dev = 0;
  hipGetDevice(&dev);
  int coop = 0;
  hipDeviceGetAttribute(&coop, hipDeviceAttributeCooperativeLaunch, dev);

  bool launched = false;
  if (coop) {
    void* args[] = {&x,  &w0, &b0, &w1, &b1, &w2, &b2,  &w3,   &b3,
                    &sw, &sb, &qw, &qb, &kw, &kb, &vw,  &vb,   &out,
                    &ACT0, &ACT1, &ABh, &BF};
    hipError_t err = hipLaunchCooperativeKernel((void*)mega, dim3(512),
                                                dim3(256), args, 37088, stream);
    launched = (err == hipSuccess);
    if (!launched) (void)hipGetLastError();  // clear sticky error
  }

  if (!launched) {  // R10 fallback path
    prep_kernel<<<dim3(818), dim3(256), 0, stream>>>(x, w0, w1, w2, w3, qw, kw,
                                                     vw, XH, BF);
    conv0_gemm<<<dim3(16, 16, 2), dim3(256), 256 * 80, stream>>>(XH, BF, b0,
                                                                 ACT0);
    dim3 g2(16, 32, 2);
    gemm_conv<3, 48, false><<<g2, dim3(256), 180 * 144, stream>>>(
        ACT0, BF + 1536, b1, ACT1, nullptr, nullptr, nullptr);
    gemm_conv<3, 48, false><<<g2, dim3(256), 180 * 144, stream>>>(
        ACT1, BF + 29184, b2, ACT0, nullptr, nullptr, nullptr);
    gemm_conv<2, 24, true><<<g2, dim3(256), 180 * 144 + 1536, stream>>>(
        ACT0, BF + 56832, b3, ABh, x, sw, sb);
    q_mfma<<<dim3(256), dim3(256), 0, stream>>>(ABh, BF, qb, Qh);
    attn_kernel<<<dim3(8, 32), dim3(256), 544 * 112, stream>>>(Qh, ABh, BF, kb,
                                                               vb, out);
  }
}

// Round 13
// 156.731 us; speedup vs baseline: 3.0667x; 3.0667x over previous
//
#include <hip/hip_runtime.h>
#include <math.h>

#define HH 256
#define WW 256
#define NN (HH * WW)

typedef _Float16 f16;
typedef _Float16 f16x8 __attribute__((ext_vector_type(8)));
typedef float f32x4 __attribute__((ext_vector_type(4)));

#define OQ 75264  // qkv B-frag base inside BF (f16 units)

__device__ inline float dot8p(f16x8 a, f16x8 b, float acc) {
#if __has_builtin(__builtin_amdgcn_fdot2)
  acc = __builtin_amdgcn_fdot2(__builtin_shufflevector(a, a, 0, 1),
                               __builtin_shufflevector(b, b, 0, 1), acc, false);
  acc = __builtin_amdgcn_fdot2(__builtin_shufflevector(a, a, 2, 3),
                               __builtin_shufflevector(b, b, 2, 3), acc, false);
  acc = __builtin_amdgcn_fdot2(__builtin_shufflevector(a, a, 4, 5),
                               __builtin_shufflevector(b, b, 4, 5), acc, false);
  acc = __builtin_amdgcn_fdot2(__builtin_shufflevector(a, a, 6, 7),
                               __builtin_shufflevector(b, b, 6, 7), acc, false);
  return acc;
#else
#pragma unroll
  for (int i = 0; i < 8; ++i) acc += (float)a[i] * (float)b[i];
  return acc;
#endif
}

// ---------------------------------------------------------------------------
// Weight repack element e -> BF[e].
// BF: L0 @0 [nt][lane][j]; L1 @1536 / L2 @29184 / L3 @56832
// [tap][kc][nt][lane][j]; qkv QF @OQ, KF @OQ+1024, VF @OQ+2048.
// ---------------------------------------------------------------------------
__device__ __forceinline__ float repack_elem(
    int e, const float* __restrict__ w0, const float* __restrict__ w1,
    const float* __restrict__ w2, const float* __restrict__ w3,
    const float* __restrict__ qw, const float* __restrict__ kw,
    const float* __restrict__ vw) {
  const int O1 = 1536, O2 = O1 + 27648, O3 = O2 + 27648;
  float val = 0.f;
  if (e >= OQ) {
    int idx = e - OQ;
    int mat = idx >> 10;
    int r = idx & 1023;
    int nt = r >> 9;
    int ln = (r >> 3) & 63;
    int j = r & 7;
    int nn = ln & 15, qd = ln >> 4;
    int ci = qd * 8 + j, co = nt * 16 + nn;
    const float* w = (mat == 0) ? qw : (mat == 1) ? kw : vw;
    if (ci < 24 && co < 24) val = w[co * 24 + ci];
  } else if (e < O1) {
    int j = e & 7;
    int ln = (e >> 3) & 63;
    int nt = e >> 9;
    int nn = ln & 15, qd = ln >> 4;
    int k = qd * 8 + j;
    int cout = nt * 16 + nn;
    if (k < 27) {
      int tap = k / 3, ci = k - tap * 3;
      val = w0[(cout * 3 + ci) * 9 + tap];
    }
  } else {
    const float* w;
    int COUT, idx;
    if (e < O2)      { w = w1; COUT = 48; idx = e - O1; }
    else if (e < O3) { w = w2; COUT = 48; idx = e - O2; }
    else             { w = w3; COUT = 24; idx = e - O3; }
    const int NT = (COUT == 48) ? 3 : 2;
    int j = idx & 7;
    int ln = (idx >> 3) & 63;
    int rest = idx >> 9;
    int nt = rest % NT;
    int q2 = rest / NT;
    int kc = q2 & 1;
    int tap = q2 >> 1;
    int nn = ln & 15, qd = ln >> 4;
    int ci = kc * 32 + qd * 8 + j;
    int cout = nt * 16 + nn;
    if (ci < 48 && cout < COUT) val = w[(cout * 48 + ci) * 9 + tap];
  }
  return val;
}

__global__ __launch_bounds__(256) void prep(
    const float* __restrict__ w0, const float* __restrict__ w1,
    const float* __restrict__ w2, const float* __restrict__ w3,
    const float* __restrict__ qw, const float* __restrict__ kw,
    const float* __restrict__ vw, f16* __restrict__ bf) {
  int e = blockIdx.x * 256 + threadIdx.x;  // 306*256 = 78336 exactly
  bf[e] = (f16)repack_elem(e, w0, w1, w2, w3, qw, kw, vw);
}

// ---------------------------------------------------------------------------
// Middle conv stage (48->48), LDS->LDS, flattened-pixel M-tiles.
// Input slots 112B (56 f16): ch 0..47 valid; pads non-NaN (LDS pre-zeroed).
// A-frag kc=1,quad>=2 reads ci>=48 garbage x B=0 (repack zero-fills) = 0.
// Out-of-image pixels stored as 0 (conv zero-padding semantics).
// ---------------------------------------------------------------------------
template <int W_IN, int W_OUT, int H_OUT, int MAXT>
__device__ __forceinline__ void stage_mid(const f16* __restrict__ inb,
                                          f16* __restrict__ outb,
                                          const f16* __restrict__ bfr,
                                          const float* __restrict__ bias,
                                          int gy0, int gx0, int tid) {
  const int P = W_OUT * H_OUT;
  const int T = (P + 15) >> 4;
  const int lane = tid & 63, wave = tid >> 6;
  const int n = lane & 15, quad = lane >> 4;
  f32x4 acc[MAXT][3];
  int ay[MAXT], ax[MAXT];
#pragma unroll
  for (int ti = 0; ti < MAXT; ++ti) {
    int t = wave + 4 * ti;
    int qa = t * 16 + n;
    if (qa > P - 1) qa = P - 1;
    ay[ti] = qa / W_OUT;
    ax[ti] = qa - ay[ti] * W_OUT;
#pragma unroll
    for (int nt = 0; nt < 3; ++nt) {
      float bv = bias[nt * 16 + n];
      acc[ti][nt] = (f32x4){bv, bv, bv, bv};
    }
  }
#pragma unroll 1
  for (int tap = 0; tap < 9; ++tap) {
    const int dy = tap / 3, dx = tap - dy * 3;
    f16x8 B[2][3];
#pragma unroll
    for (int kc = 0; kc < 2; ++kc)
#pragma unroll
      for (int nt = 0; nt < 3; ++nt)
        B[kc][nt] =
            *(const f16x8*)(bfr + (((tap * 2 + kc) * 3 + nt) * 64 + lane) * 8);
#pragma unroll
    for (int ti = 0; ti < MAXT; ++ti) {
      if (wave + 4 * ti < T) {
        const f16* ap = inb + ((ay[ti] + dy) * W_IN + ax[ti] + dx) * 56 +
                        quad * 8;
        f16x8 a0 = *(const f16x8*)(ap);
        f16x8 a1 = *(const f16x8*)(ap + 32);
#pragma unroll
        for (int nt = 0; nt < 3; ++nt)
          acc[ti][nt] = __builtin_amdgcn_mfma_f32_16x16x32_f16(
              a0, B[0][nt], acc[ti][nt], 0, 0, 0);
#pragma unroll
        for (int nt = 0; nt < 3; ++nt)
          acc[ti][nt] = __builtin_amdgcn_mfma_f32_16x16x32_f16(
              a1, B[1][nt], acc[ti][nt], 0, 0, 0);
      }
    }
  }
#pragma unroll
  for (int ti = 0; ti < MAXT; ++ti) {
    int t = wave + 4 * ti;
    if (t < T) {
#pragma unroll
      for (int reg = 0; reg < 4; ++reg) {
        int q = t * 16 + quad * 4 + reg;
        if (q < P) {
          int qy = q / W_OUT, qx = q - qy * W_OUT;
          int gy = gy0 + qy, gx = gx0 + qx;
          bool im = (gy >= 0 && gy < HH && gx >= 0 && gx < WW);
#pragma unroll
          for (int nt = 0; nt < 3; ++nt) {
            float v = im ? fmaxf(acc[ti][nt][reg], 0.f) : 0.f;
            outb[q * 56 + nt * 16 + n] = (f16)v;
          }
        }
      }
    }
  }
}

// ---------------------------------------------------------------------------
// FUSED CONV CHAIN: one block per final 16x8 tile (1024 blocks = 512 tiles x
// 2 streams). Stages ping-pong via LDS with halo recompute (no global sync,
// no intermediate global tensors — R12 showed grid.sync costs ~55 µs each,
// and R10's ACT round-trips + 6 kernel boundaries were the hidden ~80 µs).
// bufA @0: 308x112B (S0 out 22x14; later S2 out 18x10 overlay).
// bufB @34496: im2col 308x80B, later S1 out 20x12 x112B. Total 61440B.
// All LDS zeroed first (NaN x 0-weight hazard in pad channels).
// ---------------------------------------------------------------------------
__global__ __launch_bounds__(256, 2) void fused_conv(
    const float* __restrict__ x, const float* __restrict__ b0,
    const float* __restrict__ b1, const float* __restrict__ b2,
    const float* __restrict__ b3, const float* __restrict__ sw,
    const float* __restrict__ sb, f16* __restrict__ ABh,
    const f16* __restrict__ BF) {
  extern __shared__ char smem[];
  f16* bufA = (f16*)smem;
  f16* bufB = (f16*)(smem + 34496);
  const int tid = threadIdx.x;
  const int bz = blockIdx.x;
  const int z = bz >> 9, tt = bz & 511;
  const int bx = (tt & 15) * 16, by = (tt >> 4) * 8;
  const int lane = tid & 63, wave = tid >> 6;
  const int n = lane & 15, quad = lane >> 4;
  const float* xz = x + (size_t)z * 3 * NN;

  // zero all LDS (61440 B = 3840 16B chunks)
  for (int i = tid; i < 3840; i += 256) {
    f16x8 zz = {};
    *(f16x8*)(smem + i * 16) = zz;
  }
  __syncthreads();

  // ---- S0 im2col: 22x14 region at offset (-3,-3); 27 taps + 5 zero pad
  for (int p = tid; p < 308; p += 256) {
    int py = p / 22, px = p - py * 22;
    int gy = by - 3 + py, gx = bx - 3 + px;
    f16* row = bufB + p * 40;
#pragma unroll
    for (int tap = 0; tap < 9; ++tap) {
      int dy = tap / 3, dx = tap - (tap / 3) * 3;
      int sy = gy + dy - 1, sx = gx + dx - 1;
      f16 c0 = (f16)0.f, c1 = c0, c2 = c0;
      if (sy >= 0 && sy < HH && sx >= 0 && sx < WW) {
        int o = sy * WW + sx;
        c0 = (f16)xz[o];
        c1 = (f16)xz[NN + o];
        c2 = (f16)xz[2 * NN + o];
      }
      row[tap * 3 + 0] = c0;
      row[tap * 3 + 1] = c1;
      row[tap * 3 + 2] = c2;
    }
#pragma unroll
    for (int k = 27; k < 32; ++k) row[k] = (f16)0.f;
  }
  __syncthreads();

  // ---- S0 compute: 3->48 over 308 px (20 M-tiles, 5/wave), K=32
  {
    f16x8 B0[3];
#pragma unroll
    for (int nt = 0; nt < 3; ++nt)
      B0[nt] = *(const f16x8*)(BF + (nt * 64 + lane) * 8);
    f32x4 acc[5][3];
#pragma unroll
    for (int ti = 0; ti < 5; ++ti)
#pragma unroll
      for (int nt = 0; nt < 3; ++nt) {
        float bv = b0[nt * 16 + n];
        acc[ti][nt] = (f32x4){bv, bv, bv, bv};
      }
#pragma unroll
    for (int ti = 0; ti < 5; ++ti) {
      int t = wave + 4 * ti;  // 0..19, all valid
      int qa = t * 16 + n;
      if (qa > 307) qa = 307;
      f16x8 a = *(const f16x8*)(bufB + qa * 40 + quad * 8);
#pragma unroll
      for (int nt = 0; nt < 3; ++nt)
        acc[ti][nt] = __builtin_amdgcn_mfma_f32_16x16x32_f16(a, B0[nt],
                                                             acc[ti][nt], 0,
                                                             0, 0);
    }
#pragma unroll
    for (int ti = 0; ti < 5; ++ti) {
      int t = wave + 4 * ti;
#pragma unroll
      for (int reg = 0; reg < 4; ++reg) {
        int q = t * 16 + quad * 4 + reg;
        if (q < 308) {
          int qy = q / 22, qx = q - qy * 22;
          int gy = by - 3 + qy, gx = bx - 3 + qx;
          bool im = (gy >= 0 && gy < HH && gx >= 0 && gx < WW);
#pragma unroll
          for (int nt = 0; nt < 3; ++nt) {
            float v = im ? fmaxf(acc[ti][nt][reg], 0.f) : 0.f;
            bufA[q * 56 + nt * 16 + n] = (f16)v;
          }
        }
      }
    }
  }
  __syncthreads();

  // ---- S1: 48->48, bufA(22x14) -> bufB(20x12)
  stage_mid<22, 20, 12, 4>(bufA, bufB, BF + 1536, b1, by - 2, bx - 2, tid);
  __syncthreads();
  // ---- S2: 48->48, bufB(20x12) -> bufA(18x10 overlay)
  stage_mid<20, 18, 10, 3>(bufB, bufA, BF + 29184, b2, by - 1, bx - 1, tid);
  __syncthreads();

  // ---- S3: 48->24 + 1x1 skip, bufA(18x10) -> global ABh (16x8 tile)
  {
    f32x4 acc[2][2];
    int ay[2], ax[2];
#pragma unroll
    for (int ti = 0; ti < 2; ++ti) {
      int qa = (wave + 4 * ti) * 16 + n;  // < 128
      ay[ti] = qa >> 4;
      ax[ti] = qa & 15;
#pragma unroll
      for (int nt = 0; nt < 2; ++nt) {
        int cc = nt * 16 + n;
        float bv = (cc < 24) ? b3[cc] : 0.f;
        acc[ti][nt] = (f32x4){bv, bv, bv, bv};
      }
    }
#pragma unroll 1
    for (int tap = 0; tap < 9; ++tap) {
      const int dy = tap / 3, dx = tap - dy * 3;
      f16x8 B[2][2];
#pragma unroll
      for (int kc = 0; kc < 2; ++kc)
#pragma unroll
        for (int nt = 0; nt < 2; ++nt)
          B[kc][nt] = *(const f16x8*)(BF + 56832 +
                                      (((tap * 2 + kc) * 2 + nt) * 64 + lane) *
                                          8);
#pragma unroll
      for (int ti = 0; ti < 2; ++ti) {
        const f16* ap = bufA + ((ay[ti] + dy) * 18 + ax[ti] + dx) * 56 +
                        quad * 8;
        f16x8 a0 = *(const f16x8*)(ap);
        f16x8 a1 = *(const f16x8*)(ap + 32);
#pragma unroll
        for (int nt = 0; nt < 2; ++nt)
          acc[ti][nt] = __builtin_amdgcn_mfma_f32_16x16x32_f16(
              a0, B[0][nt], acc[ti][nt], 0, 0, 0);
#pragma unroll
        for (int nt = 0; nt < 2; ++nt)
          acc[ti][nt] = __builtin_amdgcn_mfma_f32_16x16x32_f16(
              a1, B[1][nt], acc[ti][nt], 0, 0, 0);
      }
    }
    f16* oz = ABh + (size_t)z * NN * 32;
#pragma unroll
    for (int ti = 0; ti < 2; ++ti) {
      int t = wave + 4 * ti;
#pragma unroll
      for (int reg = 0; reg < 4; ++reg) {
        int q = t * 16 + quad * 4 + reg;
        int gy = by + (q >> 4), gx = bx + (q & 15);
        int o = gy * WW + gx;
        float xv0 = xz[o], xv1 = xz[NN + o], xv2 = xz[2 * NN + o];
#pragma unroll
        for (int nt = 0; nt < 2; ++nt) {
          int cc = nt * 16 + n;
          float v = 0.f;
          if (cc < 24) {
            float sk = sb[cc] + sw[cc * 3 + 0] * xv0 + sw[cc * 3 + 1] * xv1 +
                       sw[cc * 3 + 2] * xv2;
            v = fmaxf(acc[ti][nt][reg], 0.f) + sk;
          }
          oz[(size_t)o * 32 + cc] = (f16)v;
        }
      }
    }
  }
}

// ---------------------------------------------------------------------------
// Attention + fused Q (validated as mega phase 5 in R12). 16x8 tile/block,
// 512 blocks. a-halo staged, in-place K/V MFMA, split softmax (2 thr/px).
// ---------------------------------------------------------------------------
__global__ __launch_bounds__(256, 3) void attn_q(
    const f16* __restrict__ ABh, const f16* __restrict__ BF,
    const float* __restrict__ qw, const float* __restrict__ qb,
    const float* __restrict__ kb, const float* __restrict__ vb,
    float* __restrict__ out) {
  extern __shared__ char smem[];
  f16* kv = (f16*)smem;                        // 320 slots * 56 f16
  f16* Wq = (f16*)(smem + 35840);              // 576 f16
  float* Qbv = (float*)(smem + 35840 + 1152);  // 24 f32
  const int tid = threadIdx.x;
  const int lane = tid & 63, wave = tid >> 6;
  const int n = lane & 15, quad = lane >> 4;
  const int bxA = ((int)blockIdx.x & 15) * 16, byA = ((int)blockIdx.x >> 4) * 8;

  for (int i = tid; i < 576; i += 256) Wq[i] = (f16)qw[i];
  if (tid < 24) Qbv[tid] = qb[tid];

  for (int idx = tid; idx < 1232; idx += 256) {
    int slot = idx >> 2, c = idx & 3;
    int row = slot / 22, pxl = slot - row * 22;
    int gy = byA + row - 3, gx = bxA + pxl - 3;
    f16x8 v = {};
    if (gy >= 0 && gy < HH && gx >= 0 && gx < WW)
      v = *(const f16x8*)(ABh + ((size_t)(gy * WW + gx)) * 32 + c * 8);
    *(f16x8*)(kv + slot * 56 + c * 8) = v;
  }
  __syncthreads();

  const int t7 = tid & 127, half = tid >> 7;  // wave-uniform half
  const int yl = t7 >> 4, xl = t7 & 15;
  const int pg = (byA + yl) * WW + bxA + xl;

  const f16* cs = kv + ((yl + 3) * 22 + (xl + 3)) * 56;
  f16x8 a0 = *(const f16x8*)(cs);
  f16x8 a1 = *(const f16x8*)(cs + 8);
  f16x8 a2 = *(const f16x8*)(cs + 16);

  const f16* bhp = ABh + (size_t)NN * 32 + (size_t)pg * 32;
  f16x8 bb0 = *(const f16x8*)(bhp);
  f16x8 bb1 = *(const f16x8*)(bhp + 8);
  f16x8 bb2 = *(const f16x8*)(bhp + 16);
  float qf[24];
#pragma unroll
  for (int co = 0; co < 24; ++co) {
    float acc = Qbv[co];
    acc = dot8p(bb0, *(const f16x8*)(Wq + co * 24), acc);
    acc = dot8p(bb1, *(const f16x8*)(Wq + co * 24 + 8), acc);
    acc = dot8p(bb2, *(const f16x8*)(Wq + co * 24 + 16), acc);
    qf[co] = acc;
  }
  f16x8 q0, q1, q2;
#pragma unroll
  for (int c = 0; c < 8; ++c) {
    q0[c] = (f16)qf[c];
    q1[c] = (f16)qf[8 + c];
    q2[c] = (f16)qf[16 + c];
  }
  __syncthreads();  // snapshots + q done before in-place overwrite

  {
    f16x8 KF[2], VF[2];
#pragma unroll
    for (int nt = 0; nt < 2; ++nt) {
      KF[nt] = *(const f16x8*)(BF + OQ + 1024 + (nt * 64 + lane) * 8);
      VF[nt] = *(const f16x8*)(BF + OQ + 2048 + (nt * 64 + lane) * 8);
    }
    float kbias[2], vbias[2];
#pragma unroll
    for (int nt = 0; nt < 2; ++nt) {
      int cc = nt * 16 + n;
      kbias[nt] = (cc < 24) ? kb[cc] : 0.f;
      vbias[nt] = (cc < 24) ? vb[cc] : 0.f;
    }
    for (int t = wave; t < 20; t += 4) {
      f16x8 a8 = *(const f16x8*)(kv + (t * 16 + n) * 56 + quad * 8);
#pragma unroll
      for (int nt = 0; nt < 2; ++nt) {
        f32x4 ak = {kbias[nt], kbias[nt], kbias[nt], kbias[nt]};
        f32x4 av = {vbias[nt], vbias[nt], vbias[nt], vbias[nt]};
        ak = __builtin_amdgcn_mfma_f32_16x16x32_f16(a8, KF[nt], ak, 0, 0, 0);
        av = __builtin_amdgcn_mfma_f32_16x16x32_f16(a8, VF[nt], av, 0, 0, 0);
        int cc = nt * 16 + n;
        if (cc < 24) {
#pragma unroll
          for (int reg = 0; reg < 4; ++reg) {
            f16* slot = kv + (t * 16 + quad * 4 + reg) * 56;
            slot[cc] = (f16)ak[reg];
            slot[24 + cc] = (f16)av[reg];
          }
        }
      }
    }
  }
  __syncthreads();

  float s[25];
  float m = -3e38f;
#pragma unroll
  for (int i = 0; i < 25; ++i) {
    int pp = half * 25 + i;
    if (pp < 49) {
      int dy = pp / 7, dx = pp - (pp / 7) * 7;
      const f16* base = kv + ((yl + dy) * 22 + (xl + dx)) * 56;
      f16x8 k0 = *(const f16x8*)(base);
      f16x8 k1 = *(const f16x8*)(base + 8);
      f16x8 k2 = *(const f16x8*)(base + 16);
      float d = 0.f;
      d = dot8p(q0, k0, d);
      d = dot8p(q1, k1, d);
      d = dot8p(q2, k2, d);
      s[i] = d * 0.20412414523193154f;  // 1/sqrt(24)
      m = fmaxf(m, s[i]);
    } else {
      s[i] = -3e38f;
    }
  }
  float den = 0.f;
#pragma unroll
  for (int i = 0; i < 25; ++i) {
    float e = __expf(s[i] - m);
    s[i] = e;
    den += e;
  }

  f16x8 y0 = {}, y1 = {}, y2 = {};
#pragma unroll
  for (int i = 0; i < 25; ++i) {
    int pp = half * 25 + i;
    if (pp < 49) {
      int dy = pp / 7, dx = pp - (pp / 7) * 7;
      const f16* base = kv + ((yl + dy) * 22 + (xl + dx)) * 56 + 24;
      f16 wh = (f16)s[i];
      f16x8 w8 = {wh, wh, wh, wh, wh, wh, wh, wh};
      f16x8 v0 = *(const f16x8*)(base);
      f16x8 v1 = *(const f16x8*)(base + 8);
      f16x8 v2 = *(const f16x8*)(base + 16);
      y0 = v0 * w8 + y0;
      y1 = v1 * w8 + y1;
      y2 = v2 * w8 + y2;
    }
  }
  __syncthreads();  // kv reads done -> reuse as exchange

  if (half == 1) {
    f16* ex = kv + t7 * 56;
    *(f16x8*)(ex) = y0;
    *(f16x8*)(ex + 8) = y1;
    *(f16x8*)(ex + 16) = y2;
    float* mf = (float*)(ex + 24);
    mf[0] = m;
    mf[1] = den;
  }
  __syncthreads();

  if (half == 0) {
    const f16* ex = kv + t7 * 56;
    f16x8 yb0 = *(const f16x8*)(ex);
    f16x8 yb1 = *(const f16x8*)(ex + 8);
    f16x8 yb2 = *(const f16x8*)(ex + 16);
    const float* mf = (const float*)(ex + 24);
    float mB = mf[0], dB = mf[1];
    float M = fmaxf(m, mB);
    float fa = __expf(m - M), fb = __expf(mB - M);
    float inv = 1.f / (den * fa + dB * fb);
#pragma unroll
    for (int c = 0; c < 8; ++c) {
      out[(size_t)c * NN + pg] =
          ((float)y0[c] * fa + (float)yb0[c] * fb) * inv + (float)a0[c];
      out[(size_t)(8 + c) * NN + pg] =
          ((float)y1[c] * fa + (float)yb1[c] * fb) * inv + (float)a1[c];
      out[(size_t)(16 + c) * NN + pg] =
          ((float)y2[c] * fa + (float)yb2[c] * fb) * inv + (float)a2[c];
    }
  } else {
#pragma unroll
    for (int c = 0; c < 8; ++c) {
      out[(size_t)(24 + c) * NN + pg] = (float)bb0[c];
      out[(size_t)(32 + c) * NN + pg] = (float)bb1[c];
      out[(size_t)(40 + c) * NN + pg] = (float)bb2[c];
    }
  }
}

// ---------------------------------------------------------------------------
extern "C" void kernel_launch(void* const* d_in, const int* in_sizes, int n_in,
                              void* d_out, int out_size, void* d_ws,
                              size_t ws_size, hipStream_t stream) {
  const float* x = (const float*)d_in[0];
  const float* w0 = (const float*)d_in[1];
  const float* b0 = (const float*)d_in[2];
  const float* w1 = (const float*)d_in[3];
  const float* b1 = (const float*)d_in[4];
  const float* w2 = (const float*)d_in[5];
  const float* b2 = (const float*)d_in[6];
  const float* w3 = (const float*)d_in[7];
  const float* b3 = (const float*)d_in[8];
  const float* sw = (const float*)d_in[9];
  const float* sb = (const float*)d_in[10];
  const float* qw = (const float*)d_in[11];
  const float* qb = (const float*)d_in[12];
  const float* kw = (const float*)d_in[13];
  const float* kb = (const float*)d_in[14];
  const float* vw = (const float*)d_in[15];
  const float* vb = (const float*)d_in[16];
  float* out = (float*)d_out;

  f16* base = (f16*)d_ws;
  f16* ABh = base;                      // 2*NN*32 f16
  f16* BF = base + (size_t)64 * NN;     // 78336 f16

  prep<<<dim3(306), dim3(256), 0, stream>>>(w0, w1, w2, w3, qw, kw, vw, BF);
  fused_conv<<<dim3(1024), dim3(256), 61440, stream>>>(x, b0, b1, b2, b3, sw,
                                                       sb, ABh, BF);
  attn_q<<<dim3(512), dim3(256), 37088, stream>>>(ABh, BF, qw, qb, kb, vb,
                                                  out);
}

// Round 14
// 152.039 us; speedup vs baseline: 3.1613x; 1.0309x over previous
//
#include <hip/hip_runtime.h>
#include <math.h>

#define HH 256
#define WW 256
#define NN (HH * WW)

typedef _Float16 f16;
typedef _Float16 f16x4 __attribute__((ext_vector_type(4)));
typedef _Float16 f16x8 __attribute__((ext_vector_type(8)));
typedef float f32x4 __attribute__((ext_vector_type(4)));

#define OQ 75264  // qkv B-frag base inside BF (f16 units)

__device__ inline float dot8p(f16x8 a, f16x8 b, float acc) {
#if __has_builtin(__builtin_amdgcn_fdot2)
  acc = __builtin_amdgcn_fdot2(__builtin_shufflevector(a, a, 0, 1),
                               __builtin_shufflevector(b, b, 0, 1), acc, false);
  acc = __builtin_amdgcn_fdot2(__builtin_shufflevector(a, a, 2, 3),
                               __builtin_shufflevector(b, b, 2, 3), acc, false);
  acc = __builtin_amdgcn_fdot2(__builtin_shufflevector(a, a, 4, 5),
                               __builtin_shufflevector(b, b, 4, 5), acc, false);
  acc = __builtin_amdgcn_fdot2(__builtin_shufflevector(a, a, 6, 7),
                               __builtin_shufflevector(b, b, 6, 7), acc, false);
  return acc;
#else
#pragma unroll
  for (int i = 0; i < 8; ++i) acc += (float)a[i] * (float)b[i];
  return acc;
#endif
}

// ---------------------------------------------------------------------------
// Weight repack element e -> BF[e]. Layout places co on lane&15 and ci(k) on
// quad*8+j — which is simultaneously a valid MFMA B-frag (k,n) AND A-frag
// (m,k) image, so the R14 operand swap needs no repack change.
// ---------------------------------------------------------------------------
__device__ __forceinline__ float repack_elem(
    int e, const float* __restrict__ w0, const float* __restrict__ w1,
    const float* __restrict__ w2, const float* __restrict__ w3,
    const float* __restrict__ qw, const float* __restrict__ kw,
    const float* __restrict__ vw) {
  const int O1 = 1536, O2 = O1 + 27648, O3 = O2 + 27648;
  float val = 0.f;
  if (e >= OQ) {
    int idx = e - OQ;
    int mat = idx >> 10;
    int r = idx & 1023;
    int nt = r >> 9;
    int ln = (r >> 3) & 63;
    int j = r & 7;
    int nn = ln & 15, qd = ln >> 4;
    int ci = qd * 8 + j, co = nt * 16 + nn;
    const float* w = (mat == 0) ? qw : (mat == 1) ? kw : vw;
    if (ci < 24 && co < 24) val = w[co * 24 + ci];
  } else if (e < O1) {
    int j = e & 7;
    int ln = (e >> 3) & 63;
    int nt = e >> 9;
    int nn = ln & 15, qd = ln >> 4;
    int k = qd * 8 + j;
    int cout = nt * 16 + nn;
    if (k < 27) {
      int tap = k / 3, ci = k - tap * 3;
      val = w0[(cout * 3 + ci) * 9 + tap];
    }
  } else {
    const float* w;
    int COUT, idx;
    if (e < O2)      { w = w1; COUT = 48; idx = e - O1; }
    else if (e < O3) { w = w2; COUT = 48; idx = e - O2; }
    else             { w = w3; COUT = 24; idx = e - O3; }
    const int NT = (COUT == 48) ? 3 : 2;
    int j = idx & 7;
    int ln = (idx >> 3) & 63;
    int rest = idx >> 9;
    int nt = rest % NT;
    int q2 = rest / NT;
    int kc = q2 & 1;
    int tap = q2 >> 1;
    int nn = ln & 15, qd = ln >> 4;
    int ci = kc * 32 + qd * 8 + j;
    int cout = nt * 16 + nn;
    if (ci < 48 && cout < COUT) val = w[(cout * 48 + ci) * 9 + tap];
  }
  return val;
}

__global__ __launch_bounds__(256) void prep(
    const float* __restrict__ w0, const float* __restrict__ w1,
    const float* __restrict__ w2, const float* __restrict__ w3,
    const float* __restrict__ qw, const float* __restrict__ kw,
    const float* __restrict__ vw, f16* __restrict__ bf) {
  int e = blockIdx.x * 256 + threadIdx.x;  // 306*256 = 78336 exactly
  bf[e] = (f16)repack_elem(e, w0, w1, w2, w3, qw, kw, vw);
}

// ---------------------------------------------------------------------------
// Middle conv stage (48->48), LDS->LDS. R14: OPERAND-SWAPPED MFMA —
// weights are the A operand, activations B. D: pixel = lane&15 (same index
// as the activation read), channels = nt*16 + quad*4 + reg. Each thread
// packs 4 consecutive channels at one pixel -> ds_write_b64 (R13 failure:
// 4x scalar ds_write_b16 per nt dominated VALU/LDS).
// ---------------------------------------------------------------------------
template <int W_IN, int W_OUT, int H_OUT, int MAXT>
__device__ __forceinline__ void stage_mid(const f16* __restrict__ inb,
                                          f16* __restrict__ outb,
                                          const f16* __restrict__ bfr,
                                          const float* __restrict__ bias,
                                          int gy0, int gx0, int tid) {
  const int P = W_OUT * H_OUT;
  const int T = (P + 15) >> 4;
  const int lane = tid & 63, wave = tid >> 6;
  const int n = lane & 15, quad = lane >> 4;
  const int cbase = quad * 4;
  f32x4 acc[MAXT][3];
  int ay[MAXT], ax[MAXT];
  float4 bv[3];
#pragma unroll
  for (int nt = 0; nt < 3; ++nt)
    bv[nt] = *(const float4*)(bias + nt * 16 + cbase);
#pragma unroll
  for (int ti = 0; ti < MAXT; ++ti) {
    int qa = (wave + 4 * ti) * 16 + n;
    int qc = (qa > P - 1) ? (P - 1) : qa;
    ay[ti] = qc / W_OUT;
    ax[ti] = qc - ay[ti] * W_OUT;
#pragma unroll
    for (int nt = 0; nt < 3; ++nt)
      acc[ti][nt] = (f32x4){bv[nt].x, bv[nt].y, bv[nt].z, bv[nt].w};
  }
#pragma unroll 1
  for (int tap = 0; tap < 9; ++tap) {
    const int dy = tap / 3, dx = tap - dy * 3;
    f16x8 B[2][3];
#pragma unroll
    for (int kc = 0; kc < 2; ++kc)
#pragma unroll
      for (int nt = 0; nt < 3; ++nt)
        B[kc][nt] =
            *(const f16x8*)(bfr + (((tap * 2 + kc) * 3 + nt) * 64 + lane) * 8);
#pragma unroll
    for (int ti = 0; ti < MAXT; ++ti) {
      if (wave + 4 * ti < T) {
        const f16* ap = inb + ((ay[ti] + dy) * W_IN + ax[ti] + dx) * 56 +
                        quad * 8;
        f16x8 a0 = *(const f16x8*)(ap);
        f16x8 a1 = *(const f16x8*)(ap + 32);
#pragma unroll
        for (int nt = 0; nt < 3; ++nt)
          acc[ti][nt] = __builtin_amdgcn_mfma_f32_16x16x32_f16(
              B[0][nt], a0, acc[ti][nt], 0, 0, 0);
#pragma unroll
        for (int nt = 0; nt < 3; ++nt)
          acc[ti][nt] = __builtin_amdgcn_mfma_f32_16x16x32_f16(
              B[1][nt], a1, acc[ti][nt], 0, 0, 0);
      }
    }
  }
#pragma unroll
  for (int ti = 0; ti < MAXT; ++ti) {
    int qa = (wave + 4 * ti) * 16 + n;
    if (wave + 4 * ti < T && qa < P) {
      int gy = gy0 + ay[ti], gx = gx0 + ax[ti];
      bool im = (gy >= 0 && gy < HH && gx >= 0 && gx < WW);
#pragma unroll
      for (int nt = 0; nt < 3; ++nt) {
        f16x4 h;
#pragma unroll
        for (int reg = 0; reg < 4; ++reg)
          h[reg] = (f16)(im ? fmaxf(acc[ti][nt][reg], 0.f) : 0.f);
        *(f16x4*)(outb + qa * 56 + nt * 16 + cbase) = h;
      }
    }
  }
}

// ---------------------------------------------------------------------------
// FUSED CONV CHAIN (R13 structure + R14 operand swap everywhere).
// bufA @0: 308x112B; bufB @34496: im2col 308x80B, later S1 out 240x112B.
// All LDS zeroed first (never-written pad bytes must be non-NaN).
// ---------------------------------------------------------------------------
__global__ __launch_bounds__(256, 2) void fused_conv(
    const float* __restrict__ x, const float* __restrict__ b0,
    const float* __restrict__ b1, const float* __restrict__ b2,
    const float* __restrict__ b3, const float* __restrict__ sw,
    const float* __restrict__ sb, f16* __restrict__ ABh,
    const f16* __restrict__ BF) {
  extern __shared__ char smem[];
  f16* bufA = (f16*)smem;
  f16* bufB = (f16*)(smem + 34496);
  const int tid = threadIdx.x;
  const int bz = blockIdx.x;
  const int z = bz >> 9, tt = bz & 511;
  const int bx = (tt & 15) * 16, by = (tt >> 4) * 8;
  const int lane = tid & 63, wave = tid >> 6;
  const int n = lane & 15, quad = lane >> 4;
  const int cbase = quad * 4;
  const float* xz = x + (size_t)z * 3 * NN;

  for (int i = tid; i < 3840; i += 256) {
    f16x8 zz = {};
    *(f16x8*)(smem + i * 16) = zz;
  }
  __syncthreads();

  // ---- S0 im2col: 22x14 region at offset (-3,-3); 27 taps + 5 zero pad
  for (int p = tid; p < 308; p += 256) {
    int py = p / 22, px = p - py * 22;
    int gy = by - 3 + py, gx = bx - 3 + px;
    f16* row = bufB + p * 40;
#pragma unroll
    for (int tap = 0; tap < 9; ++tap) {
      int dy = tap / 3, dx = tap - (tap / 3) * 3;
      int sy = gy + dy - 1, sx = gx + dx - 1;
      f16 c0 = (f16)0.f, c1 = c0, c2 = c0;
      if (sy >= 0 && sy < HH && sx >= 0 && sx < WW) {
        int o = sy * WW + sx;
        c0 = (f16)xz[o];
        c1 = (f16)xz[NN + o];
        c2 = (f16)xz[2 * NN + o];
      }
      row[tap * 3 + 0] = c0;
      row[tap * 3 + 1] = c1;
      row[tap * 3 + 2] = c2;
    }
#pragma unroll
    for (int k = 27; k < 32; ++k) row[k] = (f16)0.f;
  }
  __syncthreads();

  // ---- S0 compute: 3->48 over 308 px (20 M-tiles, 5/wave), swapped MFMA
  {
    f16x8 B0[3];
#pragma unroll
    for (int nt = 0; nt < 3; ++nt)
      B0[nt] = *(const f16x8*)(BF + (nt * 64 + lane) * 8);
    float4 bv[3];
#pragma unroll
    for (int nt = 0; nt < 3; ++nt)
      bv[nt] = *(const float4*)(b0 + nt * 16 + cbase);
    f32x4 acc[5][3];
    int pya[5], pxa[5];
#pragma unroll
    for (int ti = 0; ti < 5; ++ti) {
      int qa = (wave + 4 * ti) * 16 + n;
      int qc = (qa > 307) ? 307 : qa;
      pya[ti] = qc / 22;
      pxa[ti] = qc - pya[ti] * 22;
#pragma unroll
      for (int nt = 0; nt < 3; ++nt)
        acc[ti][nt] = (f32x4){bv[nt].x, bv[nt].y, bv[nt].z, bv[nt].w};
    }
#pragma unroll
    for (int ti = 0; ti < 5; ++ti) {
      int qa = (wave + 4 * ti) * 16 + n;
      int qc = (qa > 307) ? 307 : qa;
      f16x8 a = *(const f16x8*)(bufB + qc * 40 + quad * 8);
#pragma unroll
      for (int nt = 0; nt < 3; ++nt)
        acc[ti][nt] = __builtin_amdgcn_mfma_f32_16x16x32_f16(B0[nt], a,
                                                             acc[ti][nt], 0,
                                                             0, 0);
    }
    __syncthreads();  // all im2col reads done before bufA overlay? (bufA
                      // disjoint from bufB, but keep ordering for S1 reads)
#pragma unroll
    for (int ti = 0; ti < 5; ++ti) {
      int qa = (wave + 4 * ti) * 16 + n;
      if (qa < 308) {
        int gy = by - 3 + pya[ti], gx = bx - 3 + pxa[ti];
        bool im = (gy >= 0 && gy < HH && gx >= 0 && gx < WW);
#pragma unroll
        for (int nt = 0; nt < 3; ++nt) {
          f16x4 h;
#pragma unroll
          for (int reg = 0; reg < 4; ++reg)
            h[reg] = (f16)(im ? fmaxf(acc[ti][nt][reg], 0.f) : 0.f);
          *(f16x4*)(bufA + qa * 56 + nt * 16 + cbase) = h;
        }
      }
    }
  }
  __syncthreads();

  // ---- S1: 48->48, bufA(22x14) -> bufB(20x12)
  stage_mid<22, 20, 12, 4>(bufA, bufB, BF + 1536, b1, by - 2, bx - 2, tid);
  __syncthreads();
  // ---- S2: 48->48, bufB(20x12) -> bufA(18x10 overlay)
  stage_mid<20, 18, 10, 3>(bufB, bufA, BF + 29184, b2, by - 1, bx - 1, tid);
  __syncthreads();

  // ---- S3: 48->24 + 1x1 skip, bufA(18x10) -> global ABh (16x8 tile)
  {
    f32x4 acc[2][2];
    int ay[2], ax[2];
    float skw0[2][4], skw1[2][4], skw2[2][4], skb4[2][4];
#pragma unroll
    for (int nt = 0; nt < 2; ++nt)
#pragma unroll
      for (int reg = 0; reg < 4; ++reg) {
        int cc = nt * 16 + cbase + reg;
        bool v = (cc < 24);
        skw0[nt][reg] = v ? sw[cc * 3 + 0] : 0.f;
        skw1[nt][reg] = v ? sw[cc * 3 + 1] : 0.f;
        skw2[nt][reg] = v ? sw[cc * 3 + 2] : 0.f;
        skb4[nt][reg] = v ? sb[cc] : 0.f;
      }
#pragma unroll
    for (int ti = 0; ti < 2; ++ti) {
      int qa = (wave + 4 * ti) * 16 + n;  // < 128
      ay[ti] = qa >> 4;
      ax[ti] = qa & 15;
#pragma unroll
      for (int nt = 0; nt < 2; ++nt) {
        int cc0 = nt * 16 + cbase;
        float4 bv = (cc0 < 24) ? *(const float4*)(b3 + cc0)
                               : make_float4(0.f, 0.f, 0.f, 0.f);
        acc[ti][nt] = (f32x4){bv.x, bv.y, bv.z, bv.w};
      }
    }
#pragma unroll 1
    for (int tap = 0; tap < 9; ++tap) {
      const int dy = tap / 3, dx = tap - dy * 3;
      f16x8 B[2][2];
#pragma unroll
      for (int kc = 0; kc < 2; ++kc)
#pragma unroll
        for (int nt = 0; nt < 2; ++nt)
          B[kc][nt] = *(const f16x8*)(BF + 56832 +
                                      (((tap * 2 + kc) * 2 + nt) * 64 + lane) *
                                          8);
#pragma unroll
      for (int ti = 0; ti < 2; ++ti) {
        const f16* ap = bufA + ((ay[ti] + dy) * 18 + ax[ti] + dx) * 56 +
                        quad * 8;
        f16x8 a0 = *(const f16x8*)(ap);
        f16x8 a1 = *(const f16x8*)(ap + 32);
#pragma unroll
        for (int nt = 0; nt < 2; ++nt)
          acc[ti][nt] = __builtin_amdgcn_mfma_f32_16x16x32_f16(
              B[0][nt], a0, acc[ti][nt], 0, 0, 0);
#pragma unroll
        for (int nt = 0; nt < 2; ++nt)
          acc[ti][nt] = __builtin_amdgcn_mfma_f32_16x16x32_f16(
              B[1][nt], a1, acc[ti][nt], 0, 0, 0);
      }
    }
    f16* oz = ABh + (size_t)z * NN * 32;
#pragma unroll
    for (int ti = 0; ti < 2; ++ti) {
      int o = (by + ay[ti]) * WW + bx + ax[ti];
      float xv0 = xz[o], xv1 = xz[NN + o], xv2 = xz[2 * NN + o];
#pragma unroll
      for (int nt = 0; nt < 2; ++nt) {
        int cc0 = nt * 16 + cbase;
        if (cc0 < 24) {
          f16x4 h;
#pragma unroll
          for (int reg = 0; reg < 4; ++reg) {
            float sk = skb4[nt][reg] + skw0[nt][reg] * xv0 +
                       skw1[nt][reg] * xv1 + skw2[nt][reg] * xv2;
            h[reg] = (f16)(fmaxf(acc[ti][nt][reg], 0.f) + sk);
          }
          *(f16x4*)(oz + (size_t)o * 32 + cc0) = h;
        }
      }
    }
    // zero pad channels 24..31 so attn's pad-channel MFMA reads are clean
#pragma unroll
    for (int ti = 0; ti < 2; ++ti) {
      int o = (by + ay[ti]) * WW + bx + ax[ti];
      if (cbase + 16 >= 24 && cbase < 16) {  // never true; placeholder
      }
      if (quad >= 2) {  // cc0 = 16+8.. -> covers 24..31 with two quads
        f16x4 zz = {};
        *(f16x4*)(oz + (size_t)o * 32 + 16 + cbase) = zz;
      }
    }
  }
}

// ---------------------------------------------------------------------------
// Attention + fused Q. R14: swapped-operand K/V MFMA -> packed f16x4 LDS
// stores (was 4x scalar b16 per nt).
// ---------------------------------------------------------------------------
__global__ __launch_bounds__(256, 3) void attn_q(
    const f16* __restrict__ ABh, const f16* __restrict__ BF,
    const float* __restrict__ qw, const float* __restrict__ qb,
    const float* __restrict__ kb, const float* __restrict__ vb,
    float* __restrict__ out) {
  extern __shared__ char smem[];
  f16* kv = (f16*)smem;                        // 320 slots * 56 f16
  f16* Wq = (f16*)(smem + 35840);              // 576 f16
  float* Qbv = (float*)(smem + 35840 + 1152);  // 24 f32
  const int tid = threadIdx.x;
  const int lane = tid & 63, wave = tid >> 6;
  const int n = lane & 15, quad = lane >> 4;
  const int cbase = quad * 4;
  const int bxA = ((int)blockIdx.x & 15) * 16, byA = ((int)blockIdx.x >> 4) * 8;

  for (int i = tid; i < 576; i += 256) Wq[i] = (f16)qw[i];
  if (tid < 24) Qbv[tid] = qb[tid];

  for (int idx = tid; idx < 1232; idx += 256) {
    int slot = idx >> 2, c = idx & 3;
    int row = slot / 22, pxl = slot - row * 22;
    int gy = byA + row - 3, gx = bxA + pxl - 3;
    f16x8 v = {};
    if (gy >= 0 && gy < HH && gx >= 0 && gx < WW)
      v = *(const f16x8*)(ABh + ((size_t)(gy * WW + gx)) * 32 + c * 8);
    *(f16x8*)(kv + slot * 56 + c * 8) = v;
  }
  __syncthreads();

  const int t7 = tid & 127, half = tid >> 7;  // wave-uniform half
  const int yl = t7 >> 4, xl = t7 & 15;
  const int pg = (byA + yl) * WW + bxA + xl;

  const f16* cs = kv + ((yl + 3) * 22 + (xl + 3)) * 56;
  f16x8 a0 = *(const f16x8*)(cs);
  f16x8 a1 = *(const f16x8*)(cs + 8);
  f16x8 a2 = *(const f16x8*)(cs + 16);

  const f16* bhp = ABh + (size_t)NN * 32 + (size_t)pg * 32;
  f16x8 bb0 = *(const f16x8*)(bhp);
  f16x8 bb1 = *(const f16x8*)(bhp + 8);
  f16x8 bb2 = *(const f16x8*)(bhp + 16);
  float qf[24];
#pragma unroll
  for (int co = 0; co < 24; ++co) {
    float acc = Qbv[co];
    acc = dot8p(bb0, *(const f16x8*)(Wq + co * 24), acc);
    acc = dot8p(bb1, *(const f16x8*)(Wq + co * 24 + 8), acc);
    acc = dot8p(bb2, *(const f16x8*)(Wq + co * 24 + 16), acc);
    qf[co] = acc;
  }
  f16x8 q0, q1, q2;
#pragma unroll
  for (int c = 0; c < 8; ++c) {
    q0[c] = (f16)qf[c];
    q1[c] = (f16)qf[8 + c];
    q2[c] = (f16)qf[16 + c];
  }
  __syncthreads();  // snapshots + q done before in-place overwrite

  {
    f16x8 KF[2], VF[2];
#pragma unroll
    for (int nt = 0; nt < 2; ++nt) {
      KF[nt] = *(const f16x8*)(BF + OQ + 1024 + (nt * 64 + lane) * 8);
      VF[nt] = *(const f16x8*)(BF + OQ + 2048 + (nt * 64 + lane) * 8);
    }
    float4 kb4[2], vb4[2];
#pragma unroll
    for (int nt = 0; nt < 2; ++nt) {
      int cc0 = nt * 16 + cbase;
      kb4[nt] = (cc0 < 24) ? *(const float4*)(kb + cc0)
                           : make_float4(0.f, 0.f, 0.f, 0.f);
      vb4[nt] = (cc0 < 24) ? *(const float4*)(vb + cc0)
                           : make_float4(0.f, 0.f, 0.f, 0.f);
    }
    for (int t = wave; t < 20; t += 4) {
      f16x8 a8 = *(const f16x8*)(kv + (t * 16 + n) * 56 + quad * 8);
      f16x4 hk[2], hv[2];
#pragma unroll
      for (int nt = 0; nt < 2; ++nt) {
        f32x4 ak = {kb4[nt].x, kb4[nt].y, kb4[nt].z, kb4[nt].w};
        f32x4 av = {vb4[nt].x, vb4[nt].y, vb4[nt].z, vb4[nt].w};
        ak = __builtin_amdgcn_mfma_f32_16x16x32_f16(KF[nt], a8, ak, 0, 0, 0);
        av = __builtin_amdgcn_mfma_f32_16x16x32_f16(VF[nt], a8, av, 0, 0, 0);
#pragma unroll
        for (int reg = 0; reg < 4; ++reg) {
          hk[nt][reg] = (f16)ak[reg];
          hv[nt][reg] = (f16)av[reg];
        }
      }
      f16* slot = kv + (t * 16 + n) * 56;
#pragma unroll
      for (int nt = 0; nt < 2; ++nt) {
        int cc0 = nt * 16 + cbase;
        if (cc0 < 24) {
          *(f16x4*)(slot + cc0) = hk[nt];       // K at f16 [0:24)
          *(f16x4*)(slot + 24 + cc0) = hv[nt];  // V at f16 [24:48)
        }
      }
    }
  }
  __syncthreads();

  float s[25];
  float m = -3e38f;
#pragma unroll
  for (int i = 0; i < 25; ++i) {
    int pp = half * 25 + i;
    if (pp < 49) {
      int dy = pp / 7, dx = pp - (pp / 7) * 7;
      const f16* base = kv + ((yl + dy) * 22 + (xl + dx)) * 56;
      f16x8 k0 = *(const f16x8*)(base);
      f16x8 k1 = *(const f16x8*)(base + 8);
      f16x8 k2 = *(const f16x8*)(base + 16);
      float d = 0.f;
      d = dot8p(q0, k0, d);
      d = dot8p(q1, k1, d);
      d = dot8p(q2, k2, d);
      s[i] = d * 0.20412414523193154f;  // 1/sqrt(24)
      m = fmaxf(m, s[i]);
    } else {
      s[i] = -3e38f;
    }
  }
  float den = 0.f;
#pragma unroll
  for (int i = 0; i < 25; ++i) {
    float e = __expf(s[i] - m);
    s[i] = e;
    den += e;
  }

  f16x8 y0 = {}, y1 = {}, y2 = {};
#pragma unroll
  for (int i = 0; i < 25; ++i) {
    int pp = half * 25 + i;
    if (pp < 49) {
      int dy = pp / 7, dx = pp - (pp / 7) * 7;
      const f16* base = kv + ((yl + dy) * 22 + (xl + dx)) * 56 + 24;
      f16 wh = (f16)s[i];
      f16x8 w8 = {wh, wh, wh, wh, wh, wh, wh, wh};
      f16x8 v0 = *(const f16x8*)(base);
      f16x8 v1 = *(const f16x8*)(base + 8);
      f16x8 v2 = *(const f16x8*)(base + 16);
      y0 = v0 * w8 + y0;
      y1 = v1 * w8 + y1;
      y2 = v2 * w8 + y2;
    }
  }
  __syncthreads();  // kv reads done -> reuse as exchange

  if (half == 1) {
    f16* ex = kv + t7 * 56;
    *(f16x8*)(ex) = y0;
    *(f16x8*)(ex + 8) = y1;
    *(f16x8*)(ex + 16) = y2;
    float* mf = (float*)(ex + 24);
    mf[0] = m;
    mf[1] = den;
  }
  __syncthreads();

  if (half == 0) {
    const f16* ex = kv + t7 * 56;
    f16x8 yb0 = *(const f16x8*)(ex);
    f16x8 yb1 = *(const f16x8*)(ex + 8);
    f16x8 yb2 = *(const f16x8*)(ex + 16);
    const float* mf = (const float*)(ex + 24);
    float mB = mf[0], dB = mf[1];
    float M = fmaxf(m, mB);
    float fa = __expf(m - M), fb = __expf(mB - M);
    float inv = 1.f / (den * fa + dB * fb);
#pragma unroll
    for (int c = 0; c < 8; ++c) {
      out[(size_t)c * NN + pg] =
          ((float)y0[c] * fa + (float)yb0[c] * fb) * inv + (float)a0[c];
      out[(size_t)(8 + c) * NN + pg] =
          ((float)y1[c] * fa + (float)yb1[c] * fb) * inv + (float)a1[c];
      out[(size_t)(16 + c) * NN + pg] =
          ((float)y2[c] * fa + (float)yb2[c] * fb) * inv + (float)a2[c];
    }
  } else {
#pragma unroll
    for (int c = 0; c < 8; ++c) {
      out[(size_t)(24 + c) * NN + pg] = (float)bb0[c];
      out[(size_t)(32 + c) * NN + pg] = (float)bb1[c];
      out[(size_t)(40 + c) * NN + pg] = (float)bb2[c];
    }
  }
}

// ---------------------------------------------------------------------------
extern "C" void kernel_launch(void* const* d_in, const int* in_sizes, int n_in,
                              void* d_out, int out_size, void* d_ws,
                              size_t ws_size, hipStream_t stream) {
  const float* x = (const float*)d_in[0];
  const float* w0 = (const float*)d_in[1];
  const float* b0 = (const float*)d_in[2];
  const float* w1 = (const float*)d_in[3];
  const float* b1 = (const float*)d_in[4];
  const float* w2 = (const float*)d_in[5];
  const float* b2 = (const float*)d_in[6];
  const float* w3 = (const float*)d_in[7];
  const float* b3 = (const float*)d_in[8];
  const float* sw = (const float*)d_in[9];
  const float* sb = (const float*)d_in[10];
  const float* qw = (const float*)d_in[11];
  const float* qb = (const float*)d_in[12];
  const float* kw = (const float*)d_in[13];
  const float* kb = (const float*)d_in[14];
  const float* vw = (const float*)d_in[15];
  const float* vb = (const float*)d_in[16];
  float* out = (float*)d_out;

  f16* base = (f16*)d_ws;
  f16* ABh = base;                   // 2*NN*32 f16
  f16* BF = base + (size_t)64 * NN;  // 78336 f16

  prep<<<dim3(306), dim3(256), 0, stream>>>(w0, w1, w2, w3, qw, kw, vw, BF);
  fused_conv<<<dim3(1024), dim3(256), 61440, stream>>>(x, b0, b1, b2, b3, sw,
                                                       sb, ABh, BF);
  attn_q<<<dim3(512), dim3(256), 37088, stream>>>(ABh, BF, qw, qb, kb, vb,
                                                  out);
}

// Round 16
// 151.842 us; speedup vs baseline: 3.1655x; 1.0013x over previous
//
#include <hip/hip_runtime.h>
#include <math.h>

#define HH 256
#define WW 256
#define NN (HH * WW)

typedef _Float16 f16;
typedef _Float16 f16x4 __attribute__((ext_vector_type(4)));
typedef _Float16 f16x8 __attribute__((ext_vector_type(8)));
typedef float f32x4 __attribute__((ext_vector_type(4)));

#define OQ 75264  // qkv B-frag base inside BF (f16 units)
#define CS 48     // conv LDS slot stride in f16 (R16: was 56; 48ch, no pad)
#define IS 36     // im2col row stride in f16 (R16: was 40)

__device__ inline float dot8p(f16x8 a, f16x8 b, float acc) {
#if __has_builtin(__builtin_amdgcn_fdot2)
  acc = __builtin_amdgcn_fdot2(__builtin_shufflevector(a, a, 0, 1),
                               __builtin_shufflevector(b, b, 0, 1), acc, false);
  acc = __builtin_amdgcn_fdot2(__builtin_shufflevector(a, a, 2, 3),
                               __builtin_shufflevector(b, b, 2, 3), acc, false);
  acc = __builtin_amdgcn_fdot2(__builtin_shufflevector(a, a, 4, 5),
                               __builtin_shufflevector(b, b, 4, 5), acc, false);
  acc = __builtin_amdgcn_fdot2(__builtin_shufflevector(a, a, 6, 7),
                               __builtin_shufflevector(b, b, 6, 7), acc, false);
  return acc;
#else
#pragma unroll
  for (int i = 0; i < 8; ++i) acc += (float)a[i] * (float)b[i];
  return acc;
#endif
}

// ---------------------------------------------------------------------------
// Weight repack element e -> BF[e]. co on lane&15, ci(k) on quad*8+j —
// valid as both MFMA B-frag and A-frag image (operand swap needs no change).
// Zero-fills ci>=48 / cout>=COUT so benign LDS overreads multiply by 0.
// ---------------------------------------------------------------------------
__device__ __forceinline__ float repack_elem(
    int e, const float* __restrict__ w0, const float* __restrict__ w1,
    const float* __restrict__ w2, const float* __restrict__ w3,
    const float* __restrict__ qw, const float* __restrict__ kw,
    const float* __restrict__ vw) {
  const int O1 = 1536, O2 = O1 + 27648, O3 = O2 + 27648;
  float val = 0.f;
  if (e >= OQ) {
    int idx = e - OQ;
    int mat = idx >> 10;
    int r = idx & 1023;
    int nt = r >> 9;
    int ln = (r >> 3) & 63;
    int j = r & 7;
    int nn = ln & 15, qd = ln >> 4;
    int ci = qd * 8 + j, co = nt * 16 + nn;
    const float* w = (mat == 0) ? qw : (mat == 1) ? kw : vw;
    if (ci < 24 && co < 24) val = w[co * 24 + ci];
  } else if (e < O1) {
    int j = e & 7;
    int ln = (e >> 3) & 63;
    int nt = e >> 9;
    int nn = ln & 15, qd = ln >> 4;
    int k = qd * 8 + j;
    int cout = nt * 16 + nn;
    if (k < 27) {
      int tap = k / 3, ci = k - tap * 3;
      val = w0[(cout * 3 + ci) * 9 + tap];
    }
  } else {
    const float* w;
    int COUT, idx;
    if (e < O2)      { w = w1; COUT = 48; idx = e - O1; }
    else if (e < O3) { w = w2; COUT = 48; idx = e - O2; }
    else             { w = w3; COUT = 24; idx = e - O3; }
    const int NT = (COUT == 48) ? 3 : 2;
    int j = idx & 7;
    int ln = (idx >> 3) & 63;
    int rest = idx >> 9;
    int nt = rest % NT;
    int q2 = rest / NT;
    int kc = q2 & 1;
    int tap = q2 >> 1;
    int nn = ln & 15, qd = ln >> 4;
    int ci = kc * 32 + qd * 8 + j;
    int cout = nt * 16 + nn;
    if (ci < 48 && cout < COUT) val = w[(cout * 48 + ci) * 9 + tap];
  }
  return val;
}

__global__ __launch_bounds__(256) void prep(
    const float* __restrict__ w0, const float* __restrict__ w1,
    const float* __restrict__ w2, const float* __restrict__ w3,
    const float* __restrict__ qw, const float* __restrict__ kw,
    const float* __restrict__ vw, f16* __restrict__ bf) {
  int e = blockIdx.x * 256 + threadIdx.x;  // 306*256 = 78336 exactly
  bf[e] = (f16)repack_elem(e, w0, w1, w2, w3, qw, kw, vw);
}

// ---------------------------------------------------------------------------
// Middle conv stage (48->48), LDS->LDS, operand-swapped MFMA (weights=A,
// activations=B): D pixel = lane&15, channels = nt*16 + quad*4 + reg ->
// packed f16x4 stores. Slot stride CS=48 f16 (quad>=2 a1 overreads spill
// <=16B into the next slot / tail pad: finite data x zero weights = 0).
// ---------------------------------------------------------------------------
template <int W_IN, int W_OUT, int H_OUT, int MAXT>
__device__ __forceinline__ void stage_mid(const f16* __restrict__ inb,
                                          f16* __restrict__ outb,
                                          const f16* __restrict__ bfr,
                                          const float* __restrict__ bias,
                                          int gy0, int gx0, int tid) {
  const int P = W_OUT * H_OUT;
  const int T = (P + 15) >> 4;
  const int lane = tid & 63, wave = tid >> 6;
  const int n = lane & 15, quad = lane >> 4;
  const int cbase = quad * 4;
  f32x4 acc[MAXT][3];
  int ay[MAXT], ax[MAXT];
  float4 bv[3];
#pragma unroll
  for (int nt = 0; nt < 3; ++nt)
    bv[nt] = *(const float4*)(bias + nt * 16 + cbase);
#pragma unroll
  for (int ti = 0; ti < MAXT; ++ti) {
    int qa = (wave + 4 * ti) * 16 + n;
    int qc = (qa > P - 1) ? (P - 1) : qa;
    ay[ti] = qc / W_OUT;
    ax[ti] = qc - ay[ti] * W_OUT;
#pragma unroll
    for (int nt = 0; nt < 3; ++nt)
      acc[ti][nt] = (f32x4){bv[nt].x, bv[nt].y, bv[nt].z, bv[nt].w};
  }
#pragma unroll 1
  for (int tap = 0; tap < 9; ++tap) {
    const int dy = tap / 3, dx = tap - dy * 3;
    f16x8 B[2][3];
#pragma unroll
    for (int kc = 0; kc < 2; ++kc)
#pragma unroll
      for (int nt = 0; nt < 3; ++nt)
        B[kc][nt] =
            *(const f16x8*)(bfr + (((tap * 2 + kc) * 3 + nt) * 64 + lane) * 8);
#pragma unroll
    for (int ti = 0; ti < MAXT; ++ti) {
      if (wave + 4 * ti < T) {
        const f16* ap = inb + ((ay[ti] + dy) * W_IN + ax[ti] + dx) * CS +
                        quad * 8;
        f16x8 a0 = *(const f16x8*)(ap);
        f16x8 a1 = *(const f16x8*)(ap + 32);
#pragma unroll
        for (int nt = 0; nt < 3; ++nt)
          acc[ti][nt] = __builtin_amdgcn_mfma_f32_16x16x32_f16(
              B[0][nt], a0, acc[ti][nt], 0, 0, 0);
#pragma unroll
        for (int nt = 0; nt < 3; ++nt)
          acc[ti][nt] = __builtin_amdgcn_mfma_f32_16x16x32_f16(
              B[1][nt], a1, acc[ti][nt], 0, 0, 0);
      }
    }
  }
#pragma unroll
  for (int ti = 0; ti < MAXT; ++ti) {
    int qa = (wave + 4 * ti) * 16 + n;
    if (wave + 4 * ti < T && qa < P) {
      int gy = gy0 + ay[ti], gx = gx0 + ax[ti];
      bool im = (gy >= 0 && gy < HH && gx >= 0 && gx < WW);
#pragma unroll
      for (int nt = 0; nt < 3; ++nt) {
        f16x4 h;
#pragma unroll
        for (int reg = 0; reg < 4; ++reg)
          h[reg] = (f16)(im ? fmaxf(acc[ti][nt][reg], 0.f) : 0.f);
        *(f16x4*)(outb + qa * CS + nt * 16 + cbase) = h;
      }
    }
  }
}

// ---------------------------------------------------------------------------
// FUSED CONV CHAIN — R14's proven 16x8 geometry, R16 slimmer strides:
// bufA @0: 308 x 96B = 29568 (S0 out 22x14; later S2 out 18x10 overlay).
// bufB @29568: im2col 308 x 72B = 22176, later S1 out 240 x 96B = 23040.
// +64B tail guard. Total 52672 B -> 3 blocks/CU (was 61440 -> 2/CU; R14
// counters: Occ 18%, Mfma 22%, VALU 27% = latency-bound at 2 waves/SIMD).
// All LDS zeroed first (im2col pad f16 + tail must be non-NaN).
// ---------------------------------------------------------------------------
__global__ __launch_bounds__(256, 3) void fused_conv(
    const float* __restrict__ x, const float* __restrict__ b0,
    const float* __restrict__ b1, const float* __restrict__ b2,
    const float* __restrict__ b3, const float* __restrict__ sw,
    const float* __restrict__ sb, f16* __restrict__ ABh,
    const f16* __restrict__ BF) {
  extern __shared__ char smem[];
  f16* bufA = (f16*)smem;
  f16* bufB = (f16*)(smem + 29568);
  const int tid = threadIdx.x;
  const int bz = blockIdx.x;
  const int z = bz >> 9, tt = bz & 511;
  const int bx = (tt & 15) * 16, by = (tt >> 4) * 8;
  const int lane = tid & 63, wave = tid >> 6;
  const int n = lane & 15, quad = lane >> 4;
  const int cbase = quad * 4;
  const float* xz = x + (size_t)z * 3 * NN;

  for (int i = tid; i < 3292; i += 256) {  // 3292*16 = 52672 B
    f16x8 zz = {};
    *(f16x8*)(smem + i * 16) = zz;
  }
  __syncthreads();

  // ---- S0 im2col: 22x14 region at offset (-3,-3); 27 taps + 5 zero pad
  for (int p = tid; p < 308; p += 256) {
    int py = p / 22, px = p - py * 22;
    int gy = by - 3 + py, gx = bx - 3 + px;
    f16* row = bufB + p * IS;
#pragma unroll
    for (int tap = 0; tap < 9; ++tap) {
      int dy = tap / 3, dx = tap - (tap / 3) * 3;
      int sy = gy + dy - 1, sx = gx + dx - 1;
      f16 c0 = (f16)0.f, c1 = c0, c2 = c0;
      if (sy >= 0 && sy < HH && sx >= 0 && sx < WW) {
        int o = sy * WW + sx;
        c0 = (f16)xz[o];
        c1 = (f16)xz[NN + o];
        c2 = (f16)xz[2 * NN + o];
      }
      row[tap * 3 + 0] = c0;
      row[tap * 3 + 1] = c1;
      row[tap * 3 + 2] = c2;
    }
#pragma unroll
    for (int k = 27; k < 32; ++k) row[k] = (f16)0.f;
  }
  __syncthreads();

  // ---- S0 compute: 3->48 over 308 px (20 M-tiles, 5/wave), swapped MFMA
  {
    f16x8 B0[3];
#pragma unroll
    for (int nt = 0; nt < 3; ++nt)
      B0[nt] = *(const f16x8*)(BF + (nt * 64 + lane) * 8);
    float4 bv[3];
#pragma unroll
    for (int nt = 0; nt < 3; ++nt)
      bv[nt] = *(const float4*)(b0 + nt * 16 + cbase);
    f32x4 acc[5][3];
    int pya[5], pxa[5];
#pragma unroll
    for (int ti = 0; ti < 5; ++ti) {
      int qa = (wave + 4 * ti) * 16 + n;
      int qc = (qa > 307) ? 307 : qa;
      pya[ti] = qc / 22;
      pxa[ti] = qc - pya[ti] * 22;
#pragma unroll
      for (int nt = 0; nt < 3; ++nt)
        acc[ti][nt] = (f32x4){bv[nt].x, bv[nt].y, bv[nt].z, bv[nt].w};
    }
#pragma unroll
    for (int ti = 0; ti < 5; ++ti) {
      int qa = (wave + 4 * ti) * 16 + n;
      int qc = (qa > 307) ? 307 : qa;
      f16x8 a = *(const f16x8*)(bufB + qc * IS + quad * 8);
#pragma unroll
      for (int nt = 0; nt < 3; ++nt)
        acc[ti][nt] = __builtin_amdgcn_mfma_f32_16x16x32_f16(B0[nt], a,
                                                             acc[ti][nt], 0,
                                                             0, 0);
    }
    __syncthreads();
#pragma unroll
    for (int ti = 0; ti < 5; ++ti) {
      int qa = (wave + 4 * ti) * 16 + n;
      if (qa < 308) {
        int gy = by - 3 + pya[ti], gx = bx - 3 + pxa[ti];
        bool im = (gy >= 0 && gy < HH && gx >= 0 && gx < WW);
#pragma unroll
        for (int nt = 0; nt < 3; ++nt) {
          f16x4 h;
#pragma unroll
          for (int reg = 0; reg < 4; ++reg)
            h[reg] = (f16)(im ? fmaxf(acc[ti][nt][reg], 0.f) : 0.f);
          *(f16x4*)(bufA + qa * CS + nt * 16 + cbase) = h;
        }
      }
    }
  }
  __syncthreads();

  // ---- S1: 48->48, bufA(22x14) -> bufB(20x12)
  stage_mid<22, 20, 12, 4>(bufA, bufB, BF + 1536, b1, by - 2, bx - 2, tid);
  __syncthreads();
  // ---- S2: 48->48, bufB(20x12) -> bufA(18x10 overlay)
  stage_mid<20, 18, 10, 3>(bufB, bufA, BF + 29184, b2, by - 1, bx - 1, tid);
  __syncthreads();

  // ---- S3: 48->24 + 1x1 skip, bufA(18x10) -> global ABh (16x8 tile)
  {
    f32x4 acc[2][2];
    int ay[2], ax[2];
    float skw0[2][4], skw1[2][4], skw2[2][4], skb4[2][4];
#pragma unroll
    for (int nt = 0; nt < 2; ++nt)
#pragma unroll
      for (int reg = 0; reg < 4; ++reg) {
        int cc = nt * 16 + cbase + reg;
        bool v = (cc < 24);
        skw0[nt][reg] = v ? sw[cc * 3 + 0] : 0.f;
        skw1[nt][reg] = v ? sw[cc * 3 + 1] : 0.f;
        skw2[nt][reg] = v ? sw[cc * 3 + 2] : 0.f;
        skb4[nt][reg] = v ? sb[cc] : 0.f;
      }
#pragma unroll
    for (int ti = 0; ti < 2; ++ti) {
      int qa = (wave + 4 * ti) * 16 + n;  // < 128
      ay[ti] = qa >> 4;
      ax[ti] = qa & 15;
#pragma unroll
      for (int nt = 0; nt < 2; ++nt) {
        int cc0 = nt * 16 + cbase;
        float4 bv = (cc0 < 24) ? *(const float4*)(b3 + cc0)
                               : make_float4(0.f, 0.f, 0.f, 0.f);
        acc[ti][nt] = (f32x4){bv.x, bv.y, bv.z, bv.w};
      }
    }
#pragma unroll 1
    for (int tap = 0; tap < 9; ++tap) {
      const int dy = tap / 3, dx = tap - dy * 3;
      f16x8 B[2][2];
#pragma unroll
      for (int kc = 0; kc < 2; ++kc)
#pragma unroll
        for (int nt = 0; nt < 2; ++nt)
          B[kc][nt] = *(const f16x8*)(BF + 56832 +
                                      (((tap * 2 + kc) * 2 + nt) * 64 + lane) *
                                          8);
#pragma unroll
      for (int ti = 0; ti < 2; ++ti) {
        const f16* ap = bufA + ((ay[ti] + dy) * 18 + ax[ti] + dx) * CS +
                        quad * 8;
        f16x8 a0 = *(const f16x8*)(ap);
        f16x8 a1 = *(const f16x8*)(ap + 32);
#pragma unroll
        for (int nt = 0; nt < 2; ++nt)
          acc[ti][nt] = __builtin_amdgcn_mfma_f32_16x16x32_f16(
              B[0][nt], a0, acc[ti][nt], 0, 0, 0);
#pragma unroll
        for (int nt = 0; nt < 2; ++nt)
          acc[ti][nt] = __builtin_amdgcn_mfma_f32_16x16x32_f16(
              B[1][nt], a1, acc[ti][nt], 0, 0, 0);
      }
    }
    f16* oz = ABh + (size_t)z * NN * 32;
#pragma unroll
    for (int ti = 0; ti < 2; ++ti) {
      int o = (by + ay[ti]) * WW + bx + ax[ti];
      float xv0 = xz[o], xv1 = xz[NN + o], xv2 = xz[2 * NN + o];
#pragma unroll
      for (int nt = 0; nt < 2; ++nt) {
        int cc0 = nt * 16 + cbase;
        if (cc0 < 24) {
          f16x4 h;
#pragma unroll
          for (int reg = 0; reg < 4; ++reg) {
            float sk = skb4[nt][reg] + skw0[nt][reg] * xv0 +
                       skw1[nt][reg] * xv1 + skw2[nt][reg] * xv2;
            h[reg] = (f16)(fmaxf(acc[ti][nt][reg], 0.f) + sk);
          }
          *(f16x4*)(oz + (size_t)o * 32 + cc0) = h;
        }
      }
    }
    // zero pad channels 24..31 (attn reads 32ch/px chunks)
#pragma unroll
    for (int ti = 0; ti < 2; ++ti) {
      int o = (by + ay[ti]) * WW + bx + ax[ti];
      if (quad >= 2) {
        f16x4 zz = {};
        *(f16x4*)(oz + (size_t)o * 32 + 16 + cbase) = zz;
      }
    }
  }
}

// ---------------------------------------------------------------------------
// Attention + fused Q (byte-identical to R14's passing version; own 56-f16
// kv slot stride, untouched by the conv stride change).
// ---------------------------------------------------------------------------
__global__ __launch_bounds__(256, 3) void attn_q(
    const f16* __restrict__ ABh, const f16* __restrict__ BF,
    const float* __restrict__ qw, const float* __restrict__ qb,
    const float* __restrict__ kb, const float* __restrict__ vb,
    float* __restrict__ out) {
  extern __shared__ char smem[];
  f16* kv = (f16*)smem;                        // 320 slots * 56 f16
  f16* Wq = (f16*)(smem + 35840);              // 576 f16
  float* Qbv = (float*)(smem + 35840 + 1152);  // 24 f32
  const int tid = threadIdx.x;
  const int lane = tid & 63, wave = tid >> 6;
  const int n = lane & 15, quad = lane >> 4;
  const int cbase = quad * 4;
  const int bxA = ((int)blockIdx.x & 15) * 16, byA = ((int)blockIdx.x >> 4) * 8;

  for (int i = tid; i < 576; i += 256) Wq[i] = (f16)qw[i];
  if (tid < 24) Qbv[tid] = qb[tid];

  for (int idx = tid; idx < 1232; idx += 256) {
    int slot = idx >> 2, c = idx & 3;
    int row = slot / 22, pxl = slot - row * 22;
    int gy = byA + row - 3, gx = bxA + pxl - 3;
    f16x8 v = {};
    if (gy >= 0 && gy < HH && gx >= 0 && gx < WW)
      v = *(const f16x8*)(ABh + ((size_t)(gy * WW + gx)) * 32 + c * 8);
    *(f16x8*)(kv + slot * 56 + c * 8) = v;
  }
  __syncthreads();

  const int t7 = tid & 127, half = tid >> 7;  // wave-uniform half
  const int yl = t7 >> 4, xl = t7 & 15;
  const int pg = (byA + yl) * WW + bxA + xl;

  const f16* cs = kv + ((yl + 3) * 22 + (xl + 3)) * 56;
  f16x8 a0 = *(const f16x8*)(cs);
  f16x8 a1 = *(const f16x8*)(cs + 8);
  f16x8 a2 = *(const f16x8*)(cs + 16);

  const f16* bhp = ABh + (size_t)NN * 32 + (size_t)pg * 32;
  f16x8 bb0 = *(const f16x8*)(bhp);
  f16x8 bb1 = *(const f16x8*)(bhp + 8);
  f16x8 bb2 = *(const f16x8*)(bhp + 16);
  float qf[24];
#pragma unroll
  for (int co = 0; co < 24; ++co) {
    float acc = Qbv[co];
    acc = dot8p(bb0, *(const f16x8*)(Wq + co * 24), acc);
    acc = dot8p(bb1, *(const f16x8*)(Wq + co * 24 + 8), acc);
    acc = dot8p(bb2, *(const f16x8*)(Wq + co * 24 + 16), acc);
    qf[co] = acc;
  }
  f16x8 q0, q1, q2;
#pragma unroll
  for (int c = 0; c < 8; ++c) {
    q0[c] = (f16)qf[c];
    q1[c] = (f16)qf[8 + c];
    q2[c] = (f16)qf[16 + c];
  }
  __syncthreads();  // snapshots + q done before in-place overwrite

  {
    f16x8 KF[2], VF[2];
#pragma unroll
    for (int nt = 0; nt < 2; ++nt) {
      KF[nt] = *(const f16x8*)(BF + OQ + 1024 + (nt * 64 + lane) * 8);
      VF[nt] = *(const f16x8*)(BF + OQ + 2048 + (nt * 64 + lane) * 8);
    }
    float4 kb4[2], vb4[2];
#pragma unroll
    for (int nt = 0; nt < 2; ++nt) {
      int cc0 = nt * 16 + cbase;
      kb4[nt] = (cc0 < 24) ? *(const float4*)(kb + cc0)
                           : make_float4(0.f, 0.f, 0.f, 0.f);
      vb4[nt] = (cc0 < 24) ? *(const float4*)(vb + cc0)
                           : make_float4(0.f, 0.f, 0.f, 0.f);
    }
    for (int t = wave; t < 20; t += 4) {
      f16x8 a8 = *(const f16x8*)(kv + (t * 16 + n) * 56 + quad * 8);
      f16x4 hk[2], hv[2];
#pragma unroll
      for (int nt = 0; nt < 2; ++nt) {
        f32x4 ak = {kb4[nt].x, kb4[nt].y, kb4[nt].z, kb4[nt].w};
        f32x4 av = {vb4[nt].x, vb4[nt].y, vb4[nt].z, vb4[nt].w};
        ak = __builtin_amdgcn_mfma_f32_16x16x32_f16(KF[nt], a8, ak, 0, 0, 0);
        av = __builtin_amdgcn_mfma_f32_16x16x32_f16(VF[nt], a8, av, 0, 0, 0);
#pragma unroll
        for (int reg = 0; reg < 4; ++reg) {
          hk[nt][reg] = (f16)ak[reg];
          hv[nt][reg] = (f16)av[reg];
        }
      }
      f16* slot = kv + (t * 16 + n) * 56;
#pragma unroll
      for (int nt = 0; nt < 2; ++nt) {
        int cc0 = nt * 16 + cbase;
        if (cc0 < 24) {
          *(f16x4*)(slot + cc0) = hk[nt];       // K at f16 [0:24)
          *(f16x4*)(slot + 24 + cc0) = hv[nt];  // V at f16 [24:48)
        }
      }
    }
  }
  __syncthreads();

  float s[25];
  float m = -3e38f;
#pragma unroll
  for (int i = 0; i < 25; ++i) {
    int pp = half * 25 + i;
    if (pp < 49) {
      int dy = pp / 7, dx = pp - (pp / 7) * 7;
      const f16* base = kv + ((yl + dy) * 22 + (xl + dx)) * 56;
      f16x8 k0 = *(const f16x8*)(base);
      f16x8 k1 = *(const f16x8*)(base + 8);
      f16x8 k2 = *(const f16x8*)(base + 16);
      float d = 0.f;
      d = dot8p(q0, k0, d);
      d = dot8p(q1, k1, d);
      d = dot8p(q2, k2, d);
      s[i] = d * 0.20412414523193154f;  // 1/sqrt(24)
      m = fmaxf(m, s[i]);
    } else {
      s[i] = -3e38f;
    }
  }
  float den = 0.f;
#pragma unroll
  for (int i = 0; i < 25; ++i) {
    float e = __expf(s[i] - m);
    s[i] = e;
    den += e;
  }

  f16x8 y0 = {}, y1 = {}, y2 = {};
#pragma unroll
  for (int i = 0; i < 25; ++i) {
    int pp = half * 25 + i;
    if (pp < 49) {
      int dy = pp / 7, dx = pp - (pp / 7) * 7;
      const f16* base = kv + ((yl + dy) * 22 + (xl + dx)) * 56 + 24;
      f16 wh = (f16)s[i];
      f16x8 w8 = {wh, wh, wh, wh, wh, wh, wh, wh};
      f16x8 v0 = *(const f16x8*)(base);
      f16x8 v1 = *(const f16x8*)(base + 8);
      f16x8 v2 = *(const f16x8*)(base + 16);
      y0 = v0 * w8 + y0;
      y1 = v1 * w8 + y1;
      y2 = v2 * w8 + y2;
    }
  }
  __syncthreads();  // kv reads done -> reuse as exchange

  if (half == 1) {
    f16* ex = kv + t7 * 56;
    *(f16x8*)(ex) = y0;
    *(f16x8*)(ex + 8) = y1;
    *(f16x8*)(ex + 16) = y2;
    float* mf = (float*)(ex + 24);
    mf[0] = m;
    mf[1] = den;
  }
  __syncthreads();

  if (half == 0) {
    const f16* ex = kv + t7 * 56;
    f16x8 yb0 = *(const f16x8*)(ex);
    f16x8 yb1 = *(const f16x8*)(ex + 8);
    f16x8 yb2 = *(const f16x8*)(ex + 16);
    const float* mf = (const float*)(ex + 24);
    float mB = mf[0], dB = mf[1];
    float M = fmaxf(m, mB);
    float fa = __expf(m - M), fb = __expf(mB - M);
    float inv = 1.f / (den * fa + dB * fb);
#pragma unroll
    for (int c = 0; c < 8; ++c) {
      out[(size_t)c * NN + pg] =
          ((float)y0[c] * fa + (float)yb0[c] * fb) * inv + (float)a0[c];
      out[(size_t)(8 + c) * NN + pg] =
          ((float)y1[c] * fa + (float)yb1[c] * fb) * inv + (float)a1[c];
      out[(size_t)(16 + c) * NN + pg] =
          ((float)y2[c] * fa + (float)yb2[c] * fb) * inv + (float)a2[c];
    }
  } else {
#pragma unroll
    for (int c = 0; c < 8; ++c) {
      out[(size_t)(24 + c) * NN + pg] = (float)bb0[c];
      out[(size_t)(32 + c) * NN + pg] = (float)bb1[c];
      out[(size_t)(40 + c) * NN + pg] = (float)bb2[c];
    }
  }
}

// ---------------------------------------------------------------------------
extern "C" void kernel_launch(void* const* d_in, const int* in_sizes, int n_in,
                              void* d_out, int out_size, void* d_ws,
                              size_t ws_size, hipStream_t stream) {
  const float* x = (const float*)d_in[0];
  const float* w0 = (const float*)d_in[1];
  const float* b0 = (const float*)d_in[2];
  const float* w1 = (const float*)d_in[3];
  const float* b1 = (const float*)d_in[4];
  const float* w2 = (const float*)d_in[5];
  const float* b2 = (const float*)d_in[6];
  const float* w3 = (const float*)d_in[7];
  const float* b3 = (const float*)d_in[8];
  const float* sw = (const float*)d_in[9];
  const float* sb = (const float*)d_in[10];
  const float* qw = (const float*)d_in[11];
  const float* qb = (const float*)d_in[12];
  const float* kw = (const float*)d_in[13];
  const float* kb = (const float*)d_in[14];
  const float* vw = (const float*)d_in[15];
  const float* vb = (const float*)d_in[16];
  float* out = (float*)d_out;

  f16* base = (f16*)d_ws;
  f16* ABh = base;                   // 2*NN*32 f16
  f16* BF = base + (size_t)64 * NN;  // 78336 f16

  prep<<<dim3(306), dim3(256), 0, stream>>>(w0, w1, w2, w3, qw, kw, vw, BF);
  fused_conv<<<dim3(1024), dim3(256), 52672, stream>>>(x, b0, b1, b2, b3, sw,
                                                       sb, ABh, BF);
  attn_q<<<dim3(512), dim3(256), 37088, stream>>>(ABh, BF, qw, qb, kb, vb,
                                                  out);
}

// Round 17
// 150.705 us; speedup vs baseline: 3.1893x; 1.0075x over previous
//
#include <hip/hip_runtime.h>
#include <math.h>

#define HH 256
#define WW 256
#define NN (HH * WW)

typedef _Float16 f16;
typedef _Float16 f16x4 __attribute__((ext_vector_type(4)));
typedef _Float16 f16x8 __attribute__((ext_vector_type(8)));
typedef float f32x4 __attribute__((ext_vector_type(4)));

#define OQ 75264  // qkv B-frag base inside BF (f16 units)
#define CS 56     // conv LDS slot stride in f16 (R14 proven; R16's 48 regressed)
#define IS 40     // im2col row stride in f16

__device__ inline float dot8p(f16x8 a, f16x8 b, float acc) {
#if __has_builtin(__builtin_amdgcn_fdot2)
  acc = __builtin_amdgcn_fdot2(__builtin_shufflevector(a, a, 0, 1),
                               __builtin_shufflevector(b, b, 0, 1), acc, false);
  acc = __builtin_amdgcn_fdot2(__builtin_shufflevector(a, a, 2, 3),
                               __builtin_shufflevector(b, b, 2, 3), acc, false);
  acc = __builtin_amdgcn_fdot2(__builtin_shufflevector(a, a, 4, 5),
                               __builtin_shufflevector(b, b, 4, 5), acc, false);
  acc = __builtin_amdgcn_fdot2(__builtin_shufflevector(a, a, 6, 7),
                               __builtin_shufflevector(b, b, 6, 7), acc, false);
  return acc;
#else
#pragma unroll
  for (int i = 0; i < 8; ++i) acc += (float)a[i] * (float)b[i];
  return acc;
#endif
}

// ---------------------------------------------------------------------------
// Weight repack element e -> BF[e]. co on lane&15, ci(k) on quad*8+j —
// valid as both MFMA B-frag and A-frag image (operand swap needs no change).
// ---------------------------------------------------------------------------
__device__ __forceinline__ float repack_elem(
    int e, const float* __restrict__ w0, const float* __restrict__ w1,
    const float* __restrict__ w2, const float* __restrict__ w3,
    const float* __restrict__ qw, const float* __restrict__ kw,
    const float* __restrict__ vw) {
  const int O1 = 1536, O2 = O1 + 27648, O3 = O2 + 27648;
  float val = 0.f;
  if (e >= OQ) {
    int idx = e - OQ;
    int mat = idx >> 10;
    int r = idx & 1023;
    int nt = r >> 9;
    int ln = (r >> 3) & 63;
    int j = r & 7;
    int nn = ln & 15, qd = ln >> 4;
    int ci = qd * 8 + j, co = nt * 16 + nn;
    const float* w = (mat == 0) ? qw : (mat == 1) ? kw : vw;
    if (ci < 24 && co < 24) val = w[co * 24 + ci];
  } else if (e < O1) {
    int j = e & 7;
    int ln = (e >> 3) & 63;
    int nt = e >> 9;
    int nn = ln & 15, qd = ln >> 4;
    int k = qd * 8 + j;
    int cout = nt * 16 + nn;
    if (k < 27) {
      int tap = k / 3, ci = k - tap * 3;
      val = w0[(cout * 3 + ci) * 9 + tap];
    }
  } else {
    const float* w;
    int COUT, idx;
    if (e < O2)      { w = w1; COUT = 48; idx = e - O1; }
    else if (e < O3) { w = w2; COUT = 48; idx = e - O2; }
    else             { w = w3; COUT = 24; idx = e - O3; }
    const int NT = (COUT == 48) ? 3 : 2;
    int j = idx & 7;
    int ln = (idx >> 3) & 63;
    int rest = idx >> 9;
    int nt = rest % NT;
    int q2 = rest / NT;
    int kc = q2 & 1;
    int tap = q2 >> 1;
    int nn = ln & 15, qd = ln >> 4;
    int ci = kc * 32 + qd * 8 + j;
    int cout = nt * 16 + nn;
    if (ci < 48 && cout < COUT) val = w[(cout * 48 + ci) * 9 + tap];
  }
  return val;
}

__global__ __launch_bounds__(256) void prep(
    const float* __restrict__ w0, const float* __restrict__ w1,
    const float* __restrict__ w2, const float* __restrict__ w3,
    const float* __restrict__ qw, const float* __restrict__ kw,
    const float* __restrict__ vw, f16* __restrict__ bf) {
  int e = blockIdx.x * 256 + threadIdx.x;  // 306*256 = 78336 exactly
  bf[e] = (f16)repack_elem(e, w0, w1, w2, w3, qw, kw, vw);
}

// ---------------------------------------------------------------------------
// Middle conv stage (48->48), LDS->LDS, operand-swapped MFMA. R17: depth-1
// SOFTWARE PIPELINE on the per-tap weight loads — Bn (tap+1) issues before
// the tap-t MFMA chain, so the ~27 per-block global-weight waits collapse to
// ~1 (R14/R16 counters: ~87% stall, occupancy levers falsified twice; the
// serial load->wait->MFMA chain is the remaining suspect).
// ---------------------------------------------------------------------------
template <int W_IN, int W_OUT, int H_OUT, int MAXT>
__device__ __forceinline__ void stage_mid(const f16* __restrict__ inb,
                                          f16* __restrict__ outb,
                                          const f16* __restrict__ bfr,
                                          const float* __restrict__ bias,
                                          int gy0, int gx0, int tid) {
  const int P = W_OUT * H_OUT;
  const int T = (P + 15) >> 4;
  const int lane = tid & 63, wave = tid >> 6;
  const int n = lane & 15, quad = lane >> 4;
  const int cbase = quad * 4;
  f32x4 acc[MAXT][3];
  int ay[MAXT], ax[MAXT];

  // prologue: tap-0 weights in flight while addresses/bias set up
  f16x8 Bc[2][3];
#pragma unroll
  for (int kc = 0; kc < 2; ++kc)
#pragma unroll
    for (int nt = 0; nt < 3; ++nt)
      Bc[kc][nt] = *(const f16x8*)(bfr + ((kc * 3 + nt) * 64 + lane) * 8);

  float4 bv[3];
#pragma unroll
  for (int nt = 0; nt < 3; ++nt)
    bv[nt] = *(const float4*)(bias + nt * 16 + cbase);
#pragma unroll
  for (int ti = 0; ti < MAXT; ++ti) {
    int qa = (wave + 4 * ti) * 16 + n;
    int qc = (qa > P - 1) ? (P - 1) : qa;
    ay[ti] = qc / W_OUT;
    ax[ti] = qc - ay[ti] * W_OUT;
#pragma unroll
    for (int nt = 0; nt < 3; ++nt)
      acc[ti][nt] = (f32x4){bv[nt].x, bv[nt].y, bv[nt].z, bv[nt].w};
  }
#pragma unroll 1
  for (int tap = 0; tap < 9; ++tap) {
    const int dy = tap / 3, dx = tap - dy * 3;
    f16x8 Bn[2][3];
    if (tap < 8) {
#pragma unroll
      for (int kc = 0; kc < 2; ++kc)
#pragma unroll
        for (int nt = 0; nt < 3; ++nt)
          Bn[kc][nt] = *(const f16x8*)(bfr + ((((tap + 1) * 2 + kc) * 3 + nt) *
                                                  64 +
                                              lane) *
                                                 8);
    }
#pragma unroll
    for (int ti = 0; ti < MAXT; ++ti) {
      if (wave + 4 * ti < T) {
        const f16* ap = inb + ((ay[ti] + dy) * W_IN + ax[ti] + dx) * CS +
                        quad * 8;
        f16x8 a0 = *(const f16x8*)(ap);
        f16x8 a1 = *(const f16x8*)(ap + 32);
#pragma unroll
        for (int nt = 0; nt < 3; ++nt)
          acc[ti][nt] = __builtin_amdgcn_mfma_f32_16x16x32_f16(
              Bc[0][nt], a0, acc[ti][nt], 0, 0, 0);
#pragma unroll
        for (int nt = 0; nt < 3; ++nt)
          acc[ti][nt] = __builtin_amdgcn_mfma_f32_16x16x32_f16(
              Bc[1][nt], a1, acc[ti][nt], 0, 0, 0);
      }
    }
    if (tap < 8) {
#pragma unroll
      for (int kc = 0; kc < 2; ++kc)
#pragma unroll
        for (int nt = 0; nt < 3; ++nt) Bc[kc][nt] = Bn[kc][nt];
    }
  }
#pragma unroll
  for (int ti = 0; ti < MAXT; ++ti) {
    int qa = (wave + 4 * ti) * 16 + n;
    if (wave + 4 * ti < T && qa < P) {
      int gy = gy0 + ay[ti], gx = gx0 + ax[ti];
      bool im = (gy >= 0 && gy < HH && gx >= 0 && gx < WW);
#pragma unroll
      for (int nt = 0; nt < 3; ++nt) {
        f16x4 h;
#pragma unroll
        for (int reg = 0; reg < 4; ++reg)
          h[reg] = (f16)(im ? fmaxf(acc[ti][nt][reg], 0.f) : 0.f);
        *(f16x4*)(outb + qa * CS + nt * 16 + cbase) = h;
      }
    }
  }
}

// ---------------------------------------------------------------------------
// FUSED CONV CHAIN — R14's proven geometry (16x8 tile, 112B slots, 61440B
// LDS, 2 blocks/CU) + R17 weight-load pipelining in all tap loops.
// bufA @0: 308x112B; bufB @34496: im2col 308x80B, later S1 out 240x112B.
// All LDS zeroed first (pad bytes must be non-NaN).
// ---------------------------------------------------------------------------
__global__ __launch_bounds__(256, 2) void fused_conv(
    const float* __restrict__ x, const float* __restrict__ b0,
    const float* __restrict__ b1, const float* __restrict__ b2,
    const float* __restrict__ b3, const float* __restrict__ sw,
    const float* __restrict__ sb, f16* __restrict__ ABh,
    const f16* __restrict__ BF) {
  extern __shared__ char smem[];
  f16* bufA = (f16*)smem;
  f16* bufB = (f16*)(smem + 34496);
  const int tid = threadIdx.x;
  const int bz = blockIdx.x;
  const int z = bz >> 9, tt = bz & 511;
  const int bx = (tt & 15) * 16, by = (tt >> 4) * 8;
  const int lane = tid & 63, wave = tid >> 6;
  const int n = lane & 15, quad = lane >> 4;
  const int cbase = quad * 4;
  const float* xz = x + (size_t)z * 3 * NN;

  // S0 weights issued at entry: they load under the zero+staging phase.
  f16x8 B0[3];
#pragma unroll
  for (int nt = 0; nt < 3; ++nt)
    B0[nt] = *(const f16x8*)(BF + (nt * 64 + lane) * 8);

  for (int i = tid; i < 3840; i += 256) {  // 61440 B
    f16x8 zz = {};
    *(f16x8*)(smem + i * 16) = zz;
  }
  __syncthreads();

  // ---- S0 im2col: 22x14 region at offset (-3,-3); 27 taps + 5 zero pad
  for (int p = tid; p < 308; p += 256) {
    int py = p / 22, px = p - py * 22;
    int gy = by - 3 + py, gx = bx - 3 + px;
    f16* row = bufB + p * IS;
#pragma unroll
    for (int tap = 0; tap < 9; ++tap) {
      int dy = tap / 3, dx = tap - (tap / 3) * 3;
      int sy = gy + dy - 1, sx = gx + dx - 1;
      f16 c0 = (f16)0.f, c1 = c0, c2 = c0;
      if (sy >= 0 && sy < HH && sx >= 0 && sx < WW) {
        int o = sy * WW + sx;
        c0 = (f16)xz[o];
        c1 = (f16)xz[NN + o];
        c2 = (f16)xz[2 * NN + o];
      }
      row[tap * 3 + 0] = c0;
      row[tap * 3 + 1] = c1;
      row[tap * 3 + 2] = c2;
    }
#pragma unroll
    for (int k = 27; k < 32; ++k) row[k] = (f16)0.f;
  }
  __syncthreads();

  // ---- S0 compute: 3->48 over 308 px (20 M-tiles, 5/wave), swapped MFMA
  {
    float4 bv[3];
#pragma unroll
    for (int nt = 0; nt < 3; ++nt)
      bv[nt] = *(const float4*)(b0 + nt * 16 + cbase);
    f32x4 acc[5][3];
    int pya[5], pxa[5];
#pragma unroll
    for (int ti = 0; ti < 5; ++ti) {
      int qa = (wave + 4 * ti) * 16 + n;
      int qc = (qa > 307) ? 307 : qa;
      pya[ti] = qc / 22;
      pxa[ti] = qc - pya[ti] * 22;
#pragma unroll
      for (int nt = 0; nt < 3; ++nt)
        acc[ti][nt] = (f32x4){bv[nt].x, bv[nt].y, bv[nt].z, bv[nt].w};
    }
#pragma unroll
    for (int ti = 0; ti < 5; ++ti) {
      int qa = (wave + 4 * ti) * 16 + n;
      int qc = (qa > 307) ? 307 : qa;
      f16x8 a = *(const f16x8*)(bufB + qc * IS + quad * 8);
#pragma unroll
      for (int nt = 0; nt < 3; ++nt)
        acc[ti][nt] = __builtin_amdgcn_mfma_f32_16x16x32_f16(B0[nt], a,
                                                             acc[ti][nt], 0,
                                                             0, 0);
    }
    __syncthreads();
#pragma unroll
    for (int ti = 0; ti < 5; ++ti) {
      int qa = (wave + 4 * ti) * 16 + n;
      if (qa < 308) {
        int gy = by - 3 + pya[ti], gx = bx - 3 + pxa[ti];
        bool im = (gy >= 0 && gy < HH && gx >= 0 && gx < WW);
#pragma unroll
        for (int nt = 0; nt < 3; ++nt) {
          f16x4 h;
#pragma unroll
          for (int reg = 0; reg < 4; ++reg)
            h[reg] = (f16)(im ? fmaxf(acc[ti][nt][reg], 0.f) : 0.f);
          *(f16x4*)(bufA + qa * CS + nt * 16 + cbase) = h;
        }
      }
    }
  }
  __syncthreads();

  // ---- S1: 48->48, bufA(22x14) -> bufB(20x12)
  stage_mid<22, 20, 12, 4>(bufA, bufB, BF + 1536, b1, by - 2, bx - 2, tid);
  __syncthreads();
  // ---- S2: 48->48, bufB(20x12) -> bufA(18x10 overlay)
  stage_mid<20, 18, 10, 3>(bufB, bufA, BF + 29184, b2, by - 1, bx - 1, tid);
  __syncthreads();

  // ---- S3: 48->24 + 1x1 skip, bufA(18x10) -> global ABh (16x8 tile)
  {
    f32x4 acc[2][2];
    int ay[2], ax[2];
    // prologue tap-0 weights
    f16x8 Bc[2][2];
#pragma unroll
    for (int kc = 0; kc < 2; ++kc)
#pragma unroll
      for (int nt = 0; nt < 2; ++nt)
        Bc[kc][nt] =
            *(const f16x8*)(BF + 56832 + ((kc * 2 + nt) * 64 + lane) * 8);
    float skw0[2][4], skw1[2][4], skw2[2][4], skb4[2][4];
#pragma unroll
    for (int nt = 0; nt < 2; ++nt)
#pragma unroll
      for (int reg = 0; reg < 4; ++reg) {
        int cc = nt * 16 + cbase + reg;
        bool v = (cc < 24);
        skw0[nt][reg] = v ? sw[cc * 3 + 0] : 0.f;
        skw1[nt][reg] = v ? sw[cc * 3 + 1] : 0.f;
        skw2[nt][reg] = v ? sw[cc * 3 + 2] : 0.f;
        skb4[nt][reg] = v ? sb[cc] : 0.f;
      }
#pragma unroll
    for (int ti = 0; ti < 2; ++ti) {
      int qa = (wave + 4 * ti) * 16 + n;  // < 128
      ay[ti] = qa >> 4;
      ax[ti] = qa & 15;
#pragma unroll
      for (int nt = 0; nt < 2; ++nt) {
        int cc0 = nt * 16 + cbase;
        float4 bv = (cc0 < 24) ? *(const float4*)(b3 + cc0)
                               : make_float4(0.f, 0.f, 0.f, 0.f);
        acc[ti][nt] = (f32x4){bv.x, bv.y, bv.z, bv.w};
      }
    }
#pragma unroll 1
    for (int tap = 0; tap < 9; ++tap) {
      const int dy = tap / 3, dx = tap - dy * 3;
      f16x8 Bn[2][2];
      if (tap < 8) {
#pragma unroll
        for (int kc = 0; kc < 2; ++kc)
#pragma unroll
          for (int nt = 0; nt < 2; ++nt)
            Bn[kc][nt] = *(const f16x8*)(BF + 56832 +
                                         ((((tap + 1) * 2 + kc) * 2 + nt) * 64 +
                                          lane) *
                                             8);
      }
#pragma unroll
      for (int ti = 0; ti < 2; ++ti) {
        const f16* ap = bufA + ((ay[ti] + dy) * 18 + ax[ti] + dx) * CS +
                        quad * 8;
        f16x8 a0 = *(const f16x8*)(ap);
        f16x8 a1 = *(const f16x8*)(ap + 32);
#pragma unroll
        for (int nt = 0; nt < 2; ++nt)
          acc[ti][nt] = __builtin_amdgcn_mfma_f32_16x16x32_f16(
              Bc[0][nt], a0, acc[ti][nt], 0, 0, 0);
#pragma unroll
        for (int nt = 0; nt < 2; ++nt)
          acc[ti][nt] = __builtin_amdgcn_mfma_f32_16x16x32_f16(
              Bc[1][nt], a1, acc[ti][nt], 0, 0, 0);
      }
      if (tap < 8) {
#pragma unroll
        for (int kc = 0; kc < 2; ++kc)
#pragma unroll
          for (int nt = 0; nt < 2; ++nt) Bc[kc][nt] = Bn[kc][nt];
      }
    }
    f16* oz = ABh + (size_t)z * NN * 32;
#pragma unroll
    for (int ti = 0; ti < 2; ++ti) {
      int o = (by + ay[ti]) * WW + bx + ax[ti];
      float xv0 = xz[o], xv1 = xz[NN + o], xv2 = xz[2 * NN + o];
#pragma unroll
      for (int nt = 0; nt < 2; ++nt) {
        int cc0 = nt * 16 + cbase;
        if (cc0 < 24) {
          f16x4 h;
#pragma unroll
          for (int reg = 0; reg < 4; ++reg) {
            float sk = skb4[nt][reg] + skw0[nt][reg] * xv0 +
                       skw1[nt][reg] * xv1 + skw2[nt][reg] * xv2;
            h[reg] = (f16)(fmaxf(acc[ti][nt][reg], 0.f) + sk);
          }
          *(f16x4*)(oz + (size_t)o * 32 + cc0) = h;
        }
      }
    }
    // zero pad channels 24..31 (attn reads 32ch/px chunks)
#pragma unroll
    for (int ti = 0; ti < 2; ++ti) {
      int o = (by + ay[ti]) * WW + bx + ax[ti];
      if (quad >= 2) {
        f16x4 zz = {};
        *(f16x4*)(oz + (size_t)o * 32 + 16 + cbase) = zz;
      }
    }
  }
}

// ---------------------------------------------------------------------------
// Attention + fused Q (byte-identical to the passing R14/R16 version).
// ---------------------------------------------------------------------------
__global__ __launch_bounds__(256, 3) void attn_q(
    const f16* __restrict__ ABh, const f16* __restrict__ BF,
    const float* __restrict__ qw, const float* __restrict__ qb,
    const float* __restrict__ kb, const float* __restrict__ vb,
    float* __restrict__ out) {
  extern __shared__ char smem[];
  f16* kv = (f16*)smem;                        // 320 slots * 56 f16
  f16* Wq = (f16*)(smem + 35840);              // 576 f16
  float* Qbv = (float*)(smem + 35840 + 1152);  // 24 f32
  const int tid = threadIdx.x;
  const int lane = tid & 63, wave = tid >> 6;
  const int n = lane & 15, quad = lane >> 4;
  const int cbase = quad * 4;
  const int bxA = ((int)blockIdx.x & 15) * 16, byA = ((int)blockIdx.x >> 4) * 8;

  for (int i = tid; i < 576; i += 256) Wq[i] = (f16)qw[i];
  if (tid < 24) Qbv[tid] = qb[tid];

  for (int idx = tid; idx < 1232; idx += 256) {
    int slot = idx >> 2, c = idx & 3;
    int row = slot / 22, pxl = slot - row * 22;
    int gy = byA + row - 3, gx = bxA + pxl - 3;
    f16x8 v = {};
    if (gy >= 0 && gy < HH && gx >= 0 && gx < WW)
      v = *(const f16x8*)(ABh + ((size_t)(gy * WW + gx)) * 32 + c * 8);
    *(f16x8*)(kv + slot * 56 + c * 8) = v;
  }
  __syncthreads();

  const int t7 = tid & 127, half = tid >> 7;  // wave-uniform half
  const int yl = t7 >> 4, xl = t7 & 15;
  const int pg = (byA + yl) * WW + bxA + xl;

  const f16* cs = kv + ((yl + 3) * 22 + (xl + 3)) * 56;
  f16x8 a0 = *(const f16x8*)(cs);
  f16x8 a1 = *(const f16x8*)(cs + 8);
  f16x8 a2 = *(const f16x8*)(cs + 16);

  const f16* bhp = ABh + (size_t)NN * 32 + (size_t)pg * 32;
  f16x8 bb0 = *(const f16x8*)(bhp);
  f16x8 bb1 = *(const f16x8*)(bhp + 8);
  f16x8 bb2 = *(const f16x8*)(bhp + 16);
  float qf[24];
#pragma unroll
  for (int co = 0; co < 24; ++co) {
    float acc = Qbv[co];
    acc = dot8p(bb0, *(const f16x8*)(Wq + co * 24), acc);
    acc = dot8p(bb1, *(const f16x8*)(Wq + co * 24 + 8), acc);
    acc = dot8p(bb2, *(const f16x8*)(Wq + co * 24 + 16), acc);
    qf[co] = acc;
  }
  f16x8 q0, q1, q2;
#pragma unroll
  for (int c = 0; c < 8; ++c) {
    q0[c] = (f16)qf[c];
    q1[c] = (f16)qf[8 + c];
    q2[c] = (f16)qf[16 + c];
  }
  __syncthreads();  // snapshots + q done before in-place overwrite

  {
    f16x8 KF[2], VF[2];
#pragma unroll
    for (int nt = 0; nt < 2; ++nt) {
      KF[nt] = *(const f16x8*)(BF + OQ + 1024 + (nt * 64 + lane) * 8);
      VF[nt] = *(const f16x8*)(BF + OQ + 2048 + (nt * 64 + lane) * 8);
    }
    float4 kb4[2], vb4[2];
#pragma unroll
    for (int nt = 0; nt < 2; ++nt) {
      int cc0 = nt * 16 + cbase;
      kb4[nt] = (cc0 < 24) ? *(const float4*)(kb + cc0)
                           : make_float4(0.f, 0.f, 0.f, 0.f);
      vb4[nt] = (cc0 < 24) ? *(const float4*)(vb + cc0)
                           : make_float4(0.f, 0.f, 0.f, 0.f);
    }
    for (int t = wave; t < 20; t += 4) {
      f16x8 a8 = *(const f16x8*)(kv + (t * 16 + n) * 56 + quad * 8);
      f16x4 hk[2], hv[2];
#pragma unroll
      for (int nt = 0; nt < 2; ++nt) {
        f32x4 ak = {kb4[nt].x, kb4[nt].y, kb4[nt].z, kb4[nt].w};
        f32x4 av = {vb4[nt].x, vb4[nt].y, vb4[nt].z, vb4[nt].w};
        ak = __builtin_amdgcn_mfma_f32_16x16x32_f16(KF[nt], a8, ak, 0, 0, 0);
        av = __builtin_amdgcn_mfma_f32_16x16x32_f16(VF[nt], a8, av, 0, 0, 0);
#pragma unroll
        for (int reg = 0; reg < 4; ++reg) {
          hk[nt][reg] = (f16)ak[reg];
          hv[nt][reg] = (f16)av[reg];
        }
      }
      f16* slot = kv + (t * 16 + n) * 56;
#pragma unroll
      for (int nt = 0; nt < 2; ++nt) {
        int cc0 = nt * 16 + cbase;
        if (cc0 < 24) {
          *(f16x4*)(slot + cc0) = hk[nt];       // K at f16 [0:24)
          *(f16x4*)(slot + 24 + cc0) = hv[nt];  // V at f16 [24:48)
        }
      }
    }
  }
  __syncthreads();

  float s[25];
  float m = -3e38f;
#pragma unroll
  for (int i = 0; i < 25; ++i) {
    int pp = half * 25 + i;
    if (pp < 49) {
      int dy = pp / 7, dx = pp - (pp / 7) * 7;
      const f16* base = kv + ((yl + dy) * 22 + (xl + dx)) * 56;
      f16x8 k0 = *(const f16x8*)(base);
      f16x8 k1 = *(const f16x8*)(base + 8);
      f16x8 k2 = *(const f16x8*)(base + 16);
      float d = 0.f;
      d = dot8p(q0, k0, d);
      d = dot8p(q1, k1, d);
      d = dot8p(q2, k2, d);
      s[i] = d * 0.20412414523193154f;  // 1/sqrt(24)
      m = fmaxf(m, s[i]);
    } else {
      s[i] = -3e38f;
    }
  }
  float den = 0.f;
#pragma unroll
  for (int i = 0; i < 25; ++i) {
    float e = __expf(s[i] - m);
    s[i] = e;
    den += e;
  }

  f16x8 y0 = {}, y1 = {}, y2 = {};
#pragma unroll
  for (int i = 0; i < 25; ++i) {
    int pp = half * 25 + i;
    if (pp < 49) {
      int dy = pp / 7, dx = pp - (pp / 7) * 7;
      const f16* base = kv + ((yl + dy) * 22 + (xl + dx)) * 56 + 24;
      f16 wh = (f16)s[i];
      f16x8 w8 = {wh, wh, wh, wh, wh, wh, wh, wh};
      f16x8 v0 = *(const f16x8*)(base);
      f16x8 v1 = *(const f16x8*)(base + 8);
      f16x8 v2 = *(const f16x8*)(base + 16);
      y0 = v0 * w8 + y0;
      y1 = v1 * w8 + y1;
      y2 = v2 * w8 + y2;
    }
  }
  __syncthreads();  // kv reads done -> reuse as exchange

  if (half == 1) {
    f16* ex = kv + t7 * 56;
    *(f16x8*)(ex) = y0;
    *(f16x8*)(ex + 8) = y1;
    *(f16x8*)(ex + 16) = y2;
    float* mf = (float*)(ex + 24);
    mf[0] = m;
    mf[1] = den;
  }
  __syncthreads();

  if (half == 0) {
    const f16* ex = kv + t7 * 56;
    f16x8 yb0 = *(const f16x8*)(ex);
    f16x8 yb1 = *(const f16x8*)(ex + 8);
    f16x8 yb2 = *(const f16x8*)(ex + 16);
    const float* mf = (const float*)(ex + 24);
    float mB = mf[0], dB = mf[1];
    float M = fmaxf(m, mB);
    float fa = __expf(m - M), fb = __expf(mB - M);
    float inv = 1.f / (den * fa + dB * fb);
#pragma unroll
    for (int c = 0; c < 8; ++c) {
      out[(size_t)c * NN + pg] =
          ((float)y0[c] * fa + (float)yb0[c] * fb) * inv + (float)a0[c];
      out[(size_t)(8 + c) * NN + pg] =
          ((float)y1[c] * fa + (float)yb1[c] * fb) * inv + (float)a1[c];
      out[(size_t)(16 + c) * NN + pg] =
          ((float)y2[c] * fa + (float)yb2[c] * fb) * inv + (float)a2[c];
    }
  } else {
#pragma unroll
    for (int c = 0; c < 8; ++c) {
      out[(size_t)(24 + c) * NN + pg] = (float)bb0[c];
      out[(size_t)(32 + c) * NN + pg] = (float)bb1[c];
      out[(size_t)(40 + c) * NN + pg] = (float)bb2[c];
    }
  }
}

// ---------------------------------------------------------------------------
extern "C" void kernel_launch(void* const* d_in, const int* in_sizes, int n_in,
                              void* d_out, int out_size, void* d_ws,
                              size_t ws_size, hipStream_t stream) {
  const float* x = (const float*)d_in[0];
  const float* w0 = (const float*)d_in[1];
  const float* b0 = (const float*)d_in[2];
  const float* w1 = (const float*)d_in[3];
  const float* b1 = (const float*)d_in[4];
  const float* w2 = (const float*)d_in[5];
  const float* b2 = (const float*)d_in[6];
  const float* w3 = (const float*)d_in[7];
  const float* b3 = (const float*)d_in[8];
  const float* sw = (const float*)d_in[9];
  const float* sb = (const float*)d_in[10];
  const float* qw = (const float*)d_in[11];
  const float* qb = (const float*)d_in[12];
  const float* kw = (const float*)d_in[13];
  const float* kb = (const float*)d_in[14];
  const float* vw = (const float*)d_in[15];
  const float* vb = (const float*)d_in[16];
  float* out = (float*)d_out;

  f16* base = (f16*)d_ws;
  f16* ABh = base;                   // 2*NN*32 f16
  f16* BF = base + (size_t)64 * NN;  // 78336 f16

  prep<<<dim3(306), dim3(256), 0, stream>>>(w0, w1, w2, w3, qw, kw, vw, BF);
  fused_conv<<<dim3(1024), dim3(256), 61440, stream>>>(x, b0, b1, b2, b3, sw,
                                                       sb, ABh, BF);
  attn_q<<<dim3(512), dim3(256), 37088, stream>>>(ABh, BF, qw, qb, kb, vb,
                                                  out);
}